// Round 5
// baseline (336.000 us; speedup 1.0000x reference)
//
#include <hip/hip_runtime.h>
#include <cfloat>
#include <cstdint>

#define BATCH 16
#define PRIORS 3000
#define NCLS 201
#define NLBL 200           // NCLS - 1
#define TOPN 100
#define SCORE_THR 0.02f
#define NMS_THR 0.45f

// v15: ONE fused kernel. Grid (47, 16), 1024 threads. Each block filters 64
// priors (16 waves x 4 priors -- same per-wave quadruple grouping as v10-v14,
// bit-exact keys), then fence + done-counter; the LAST block of each image
// (threadfence-reduction election, device-scope atomics per G12/m20) runs the
// full NMS for that image with its 1024 threads. Image b's NMS overlaps
// later images' filtering; saves a kernel launch + the all-images barrier.
// v14 lesson applied: no atomics in the filter emit path (per-segment hot
// slots); fallback recomputes candidates from obj (never taken).
// LDS: dbox table DROPPED on the fast path (decode is a pure function ->
// re-decode for qbox/output; fmax reduction order-exact). Fallback aliases
// dbox over the adjacency region (strictly after fast path). ~60 KB/block
// -> 2 blocks/CU = 2048 thr/CU for the filter phase.
#define PPB 64                               // priors per block
#define FBLK2 ((PRIORS + PPB - 1) / PPB)     // 47 blocks/image
#define WPB 16                               // waves per block
#define SEGW 64                              // seg slots per wave-segment (fallback)
#define SEGS (FBLK2 * WPB)                   // 752 segments/image
#define SLOTS (SEGS * SEGW)                  // 48128 slots/image (fallback ws)
#define HOTW 8                               // hot slots per segment
#define OVF_CAP 1024
#define T0 0.08f           // hot threshold: ~315 hot/image (in [105,512] w/ margin)

#define NMS_T 1024
#define NBINS 1024         // strata over (key>>48)-SB_BASE (fallback only)
#define HCAP 512
#define SB_BASE 0x3CA3     // floatbits(0.02) >> 16

__device__ __forceinline__ int key_stratum(uint64_t k) {
    int s = (int)(k >> 48) - SB_BASE;
    return s < 0 ? 0 : (s > NBINS - 1 ? NBINS - 1 : s);
}

// ---------------------------------------------------------------------------
// Decode one prior's box. EXACT expression match with all prior versions.
// Pure function of (deltas, priors, b, p) -> identical bits wherever called.
// ---------------------------------------------------------------------------
__device__ __forceinline__ float4 decode_box(
    const float* __restrict__ deltas, const float* __restrict__ priors,
    int b, int p)
{
    float4 d4 = ((const float4*)deltas)[(size_t)b * PRIORS + p];
    float4 pr = ((const float4*)priors)[p];
    float cx = d4.x * 0.1f * pr.z + pr.x;
    float cy = d4.y * 0.1f * pr.w + pr.y;
    float w  = expf(d4.z * 0.2f) * pr.z;
    float h  = expf(d4.w * 0.2f) * pr.w;
    return make_float4(cx - 0.5f * w, cy - 0.5f * h,
                       cx + 0.5f * w, cy + 0.5f * h);
}

// ---------------------------------------------------------------------------
// Shared softmax core: 4 priors per 64-lane wave, interleaved trees.
// EXACT expression/order match with all prior bit-exact versions.
// ---------------------------------------------------------------------------
__device__ __forceinline__ void softmax4(
    const float* __restrict__ obj, int b, int pbase, int lane,
    bool pv[4], float e0[4], float e1[4], float e2[4], float e3[4],
    float inv[4])
{
    float v0[4], v1[4], v2[4], v3[4];
#pragma unroll
    for (int pp = 0; pp < 4; ++pp) {
        int p = pbase + pp;
        pv[pp] = (p < PRIORS);
        const float* x = obj + ((size_t)b * PRIORS + (pv[pp] ? p : PRIORS - 1)) * NCLS;
        v0[pp] = x[lane];
        v1[pp] = x[lane + 64];
        v2[pp] = x[lane + 128];
        v3[pp] = (lane + 192 < NCLS) ? x[lane + 192] : -FLT_MAX;
    }
    float mx[4];
#pragma unroll
    for (int pp = 0; pp < 4; ++pp)
        mx[pp] = fmaxf(fmaxf(v0[pp], v1[pp]), fmaxf(v2[pp], v3[pp]));
    for (int d = 32; d > 0; d >>= 1) {
#pragma unroll
        for (int pp = 0; pp < 4; ++pp)
            mx[pp] = fmaxf(mx[pp], __shfl_xor(mx[pp], d, 64));
    }
    float se[4];
#pragma unroll
    for (int pp = 0; pp < 4; ++pp) {
        e0[pp] = expf(v0[pp] - mx[pp]);
        e1[pp] = expf(v1[pp] - mx[pp]);
        e2[pp] = expf(v2[pp] - mx[pp]);
        e3[pp] = (lane + 192 < NCLS) ? expf(v3[pp] - mx[pp]) : 0.0f;
        se[pp] = e0[pp] + e1[pp] + e2[pp] + e3[pp];
    }
    for (int d = 32; d > 0; d >>= 1) {
#pragma unroll
        for (int pp = 0; pp < 4; ++pp)
            se[pp] += __shfl_xor(se[pp], d, 64);
    }
#pragma unroll
    for (int pp = 0; pp < 4; ++pp) inv[pp] = 1.0f / se[pp];
}

// ---------------------------------------------------------------------------
// Wave-0 register bitonic sort of 512 u64 keys (8/lane), descending.
// ---------------------------------------------------------------------------
__device__ __forceinline__ void sort512_desc(const uint64_t* skey,
                                             uint64_t K[8], int lane)
{
#pragma unroll
    for (int r = 0; r < 8; ++r) K[r] = skey[r * 64 + lane];
#pragma unroll
    for (int k2 = 2; k2 <= 512; k2 <<= 1) {
#pragma unroll
        for (int j2 = k2 >> 1; j2 >= 64; j2 >>= 1) {     // register stages
            int j2r = j2 >> 6;
#pragma unroll
            for (int r = 0; r < 8; ++r) {
                if ((r & j2r) == 0) {
                    int rp = r | j2r;
                    bool up = ((((r << 6) + lane) & k2) == 0);
                    uint64_t a = K[r], bb = K[rp];
                    uint64_t mxk = a > bb ? a : bb;
                    uint64_t mnk = a > bb ? bb : a;
                    K[r]  = up ? mxk : mnk;
                    K[rp] = up ? mnk : mxk;
                }
            }
        }
#pragma unroll
        for (int j2 = ((k2 >> 1) < 32 ? (k2 >> 1) : 32); j2 >= 1; j2 >>= 1) {
#pragma unroll
            for (int r = 0; r < 8; ++r) {                // shuffle stages
                uint64_t o = __shfl_xor((unsigned long long)K[r], j2, 64);
                bool up = ((((r << 6) + lane) & k2) == 0);
                bool lower = ((lane & j2) == 0);
                K[r] = (up == lower) ? (K[r] > o ? K[r] : o)
                                     : (K[r] < o ? K[r] : o);
            }
        }
    }
}

// ---------------------------------------------------------------------------
// FALLBACK ONLY: wave-0 batched scan over sorted K[8] (desc).
// ---------------------------------------------------------------------------
__device__ __forceinline__ int scan_sorted_w0(
    const uint64_t K[8], int b, const float4* dbox, float ofb,
    float4* abox, float* aarea, int na, float* __restrict__ out, int lane)
{
#pragma unroll
    for (int r = 0; r < 8; ++r) {
        if (na >= TOPN) break;
        uint64_t myk = K[r];
        bool valid = (myk != 0ull);
        uint32_t oid = 0xFFFFFFFFu - (uint32_t)myk;
        int p = valid ? (int)(oid / NLBL) : 0;
        int c = valid ? ((int)(oid - (uint32_t)p * NLBL) + 1) : 1;
        float4 db = dbox[p];
        float lof = (float)c * ofb;
        float qx1 = db.x + lof, qy1 = db.y + lof;
        float qx2 = db.z + lof, qy2 = db.w + lof;
        float aq = (qx2 - qx1) * (qy2 - qy1);
        bool dead = false;
        for (int l = 0; l < na; ++l) {
            float4 a = abox[l];                    // broadcast LDS read
            float ix1 = fmaxf(qx1, a.x), iy1 = fmaxf(qy1, a.y);
            float ix2 = fminf(qx2, a.z), iy2 = fminf(qy2, a.w);
            float inter = fmaxf(ix2 - ix1, 0.0f) * fmaxf(iy2 - iy1, 0.0f);
            float iou = inter / (aq + aarea[l] - inter);  // NaN>thr==false
            if (iou > NMS_THR) dead = true;
        }
        uint64_t alive = __ballot(valid && !dead);
        while (alive != 0ull && na < TOPN) {
            int j = __ffsll((unsigned long long)alive) - 1;
            float ax1 = __shfl(qx1, j, 64);
            float ay1 = __shfl(qy1, j, 64);
            float ax2 = __shfl(qx2, j, 64);
            float ay2 = __shfl(qy2, j, 64);
            float aa  = __shfl(aq,  j, 64);
            if (lane == j) {                       // accepted lane writes
                abox[na]  = make_float4(qx1, qy1, qx2, qy2);
                aarea[na] = aq;
                float* o = out + ((size_t)b * TOPN + na) * 6;
                o[0] = fminf(fmaxf(db.x, 0.0f), 1.0f);
                o[1] = fminf(fmaxf(db.y, 0.0f), 1.0f);
                o[2] = fminf(fmaxf(db.z, 0.0f), 1.0f);
                o[3] = fminf(fmaxf(db.w, 0.0f), 1.0f);
                o[4] = __uint_as_float((uint32_t)(myk >> 32));
                o[5] = (float)c;
            }
            na++;
            bool mine = ((alive >> lane) & 1ull) != 0ull;
            bool drop = (lane == j);               // force-remove accepted
            if (mine && !drop) {
                float ix1 = fmaxf(qx1, ax1), iy1 = fmaxf(qy1, ay1);
                float ix2 = fminf(qx2, ax2), iy2 = fminf(qy2, ay2);
                float inter = fmaxf(ix2 - ix1, 0.0f) * fmaxf(iy2 - iy1, 0.0f);
                float iou = inter / (aq + aa - inter);
                if (iou > NMS_THR) drop = true;
            }
            alive = __ballot(mine && !drop);
        }
    }
    return na;
}

// ---------------------------------------------------------------------------
// Fallback single-candidate scan step (overfull-stratum path; never taken).
// ---------------------------------------------------------------------------
__device__ __forceinline__ int scan_step_w0(
    uint64_t key, int b, const float4* dbox, float ofb,
    float4* abox, float* aarea, int na, float* __restrict__ out, int lane)
{
    uint32_t oid = 0xFFFFFFFFu - (uint32_t)key;
    int p = (int)(oid / NLBL);
    int c = (int)(oid - (uint32_t)p * NLBL) + 1;
    float4 db = dbox[p];
    float lo = (float)c * ofb;
    float qx1 = db.x + lo, qy1 = db.y + lo;
    float qx2 = db.z + lo, qy2 = db.w + lo;
    float aq = (qx2 - qx1) * (qy2 - qy1);
    bool sup = false;
    for (int l = lane; l < na; l += 64) {
        float4 a = abox[l];
        float ix1 = fmaxf(qx1, a.x), iy1 = fmaxf(qy1, a.y);
        float ix2 = fminf(qx2, a.z), iy2 = fminf(qy2, a.w);
        float inter = fmaxf(ix2 - ix1, 0.0f) * fmaxf(iy2 - iy1, 0.0f);
        float iou = inter / (aq + aarea[l] - inter);
        if (iou > NMS_THR) sup = true;
    }
    if (__ballot(sup) == 0ull) {
        if (lane == 0) {
            abox[na]  = make_float4(qx1, qy1, qx2, qy2);
            aarea[na] = aq;
            float* o = out + ((size_t)b * TOPN + na) * 6;
            o[0] = fminf(fmaxf(db.x, 0.0f), 1.0f);
            o[1] = fminf(fmaxf(db.y, 0.0f), 1.0f);
            o[2] = fminf(fmaxf(db.z, 0.0f), 1.0f);
            o[3] = fminf(fmaxf(db.w, 0.0f), 1.0f);
            o[4] = __uint_as_float((uint32_t)(key >> 32));
            o[5] = (float)c;
        }
        __threadfence_block();
        return na + 1;
    }
    return na;
}

// ---------------------------------------------------------------------------
// v15 fused kernel: grid (FBLK2, BATCH), 1024 threads.
// Phase 1 (all blocks): filter 64 priors -> hot slots. Phase 2 (last block
// of each image, threadfence-reduction election): full NMS for the image.
// ---------------------------------------------------------------------------
__global__ __launch_bounds__(NMS_T) void fused_kernel(
    const float*    __restrict__ deltas,  // [B][P][4]
    const float*    __restrict__ priors,  // [P][4]
    const float*    __restrict__ obj,     // [B][P][NCLS]
    uint64_t*       __restrict__ hotS,    // [B][SEGS*HOTW]
    int*            __restrict__ flags,   // [B] hot-overflow flags (memset 0)
    int*            __restrict__ done,    // [B] block arrival counters (memset 0)
    uint64_t*       __restrict__ segWS,   // [B][SLOTS]  (fallback scratch)
    uint64_t*       __restrict__ ovfWS,   // [B][OVF_CAP](fallback scratch)
    float*          __restrict__ out)     // [B][TOPN][6]
{
    // ---- LDS: 48 KB aliased region (fast: adjB+qbox+qarea / fb: dbox) ----
    __shared__ __align__(16) char uMem[48 * 1024];
    uint64_t* adjB  = (uint64_t*)uMem;                 // 32 KB (fast)
    float4*   qbox  = (float4*)(uMem + 32 * 1024);     // 8 KB  (fast)
    float*    qarea = (float*)(uMem + 40 * 1024);      // 2 KB  (fast)
    float4*   dboxF = (float4*)uMem;                   // 48 KB (fallback only)
    __shared__ uint64_t skey[HCAP];       // collected/sorted keys (4 KB)
    __shared__ int      sufx[NBINS];      // fallback suffix counts (4 KB)
    __shared__ float4   abox[112];        // accepted boxes (fallback only)
    __shared__ float    aarea[112];
    __shared__ uint64_t rk[NMS_T / 64];   // fast: accept masks / fb: argmax
    __shared__ float    wredF[NMS_T / 64];
    __shared__ int      wtotS[NMS_T / 64];
    __shared__ int      carryS[NMS_T / 64];
    __shared__ int cntC, ovfC, loS, naS, electedS;
    __shared__ uint64_t fkS;

    const int b    = blockIdx.y;
    const int tid  = threadIdx.x;
    const int wave = tid >> 6;
    const int lane = tid & 63;

    // ================= PHASE 1: filter 64 priors =================
    {
        const int segId = blockIdx.x * WPB + wave;
        const int pbase = blockIdx.x * PPB + wave * 4;
        uint64_t* myhot = hotS + ((size_t)b * SEGS + segId) * HOTW;

        bool pv[4]; float e0[4], e1[4], e2[4], e3[4], inv[4];
        softmax4(obj, b, pbase, lane, pv, e0, e1, e2, e3, inv);

        int hcur = 0;
#pragma unroll
        for (int pp = 0; pp < 4; ++pp) {
            float ev[4] = { e0[pp], e1[pp], e2[pp], e3[pp] };
#pragma unroll
            for (int k = 0; k < 4; ++k) {
                int c = lane + 64 * k;
                float prob = ev[k] * inv[pp];
                bool hotp = pv[pp] && (c >= 1) && (c < NCLS) && (prob > T0);
                uint64_t hmask = __ballot(hotp);
                if (hotp) {
                    uint32_t oid = (uint32_t)((pbase + pp) * NLBL + (c - 1));
                    uint64_t key = ((uint64_t)__float_as_uint(prob) << 32)
                                 | (uint64_t)(0xFFFFFFFFu - oid);
                    int hidx = hcur + (int)__popcll(hmask & ((1ull << lane) - 1ull));
                    if (hidx < HOTW) myhot[hidx] = key;
                    else flags[b] = 1;         // exact: force fallback (never taken)
                }
                hcur += (int)__popcll(hmask);
            }
        }
        if (lane < HOTW && lane >= (hcur < HOTW ? hcur : HOTW)) myhot[lane] = 0ull;
    }

    // ================= election (threadfence-reduction pattern) =============
    __threadfence();                      // release our hot writes device-wide
    __syncthreads();
    if (tid == 0)
        electedS = (atomicAdd(&done[b], 1) == FBLK2 - 1) ? 1 : 0;
    __syncthreads();
    if (!electedS) return;
    __threadfence();                      // acquire: see all blocks' hot writes

    // ================= PHASE 2: NMS for image b (1024 threads) =============
    const uint64_t* hslots = hotS + (size_t)b * SEGS * HOTW;
    uint64_t* slots = segWS + (size_t)b * SLOTS;
    uint64_t* ovfp  = ovfWS + (size_t)b * OVF_CAP;

    if (tid == 0) { cntC = 0; naS = 0; }
    if (lane == 0) wredF[wave] = -FLT_MAX;
    __syncthreads();

    // ---- collect hot keys (ballot-compacted; few tiny LDS atomics) ----
    for (int j = tid; j < SEGS * HOTW; j += NMS_T) {
        uint64_t k = hslots[j];
        uint64_t m = __ballot(k != 0ull);
        if (m) {
            int base = 0;
            if (lane == 0) base = atomicAdd(&cntC, (int)__popcll(m));
            base = __shfl(base, 0, 64);
            if (k) {
                int i = base + (int)__popcll(m & ((1ull << lane) - 1ull));
                if (i < HCAP) skey[i] = k;
            }
        }
    }
    __syncthreads();
    int hc = cntC;                          // uniform
    bool fast = (flags[b] == 0) && (hc <= HCAP);

    if (fast) {
        if (tid < HCAP && tid >= hc) skey[tid] = 0ull;
        __syncthreads();
        if (wave == 0) {
            // sort 512 keys in registers, write back sorted order
            uint64_t K[8];
            sort512_desc(skey, K, lane);
#pragma unroll
            for (int r = 0; r < 8; ++r) skey[r * 64 + lane] = K[r];
        } else {
            // waves 1-15: decode 3000 priors (NO store) -> lmax only
            int base0 = (wave - 1) * 200;
            float lmax = -FLT_MAX;
            for (int p = base0 + lane; p < base0 + 200; p += 64) {
                float4 d = decode_box(deltas, priors, b, p);
                lmax = fmaxf(lmax, fmaxf(fmaxf(d.x, d.y), fmaxf(d.z, d.w)));
            }
            for (int d = 32; d > 0; d >>= 1)
                lmax = fmaxf(lmax, __shfl_xor(lmax, d, 64));
            if (lane == 0) wredF[wave] = lmax;
        }
        __syncthreads();                     // sorted skey + wredF ready

        // block-uniform ofb = max(all decoded coords) + 1 (ref's off)
        float v = wredF[lane & 15];
        for (int d = 8; d > 0; d >>= 1) v = fmaxf(v, __shfl_xor(v, d, 64));
        float ofb = v + 1.0f;

        // per-rank offset boxes + areas (re-decode; identical exprs)
        if (tid < HCAP) {
            uint64_t k = skey[tid];
            bool valid = (k != 0ull);
            uint32_t oid = 0xFFFFFFFFu - (uint32_t)k;
            int p = valid ? (int)(oid / NLBL) : 0;
            int c = valid ? ((int)(oid - (uint32_t)p * NLBL) + 1) : 1;
            float4 db = decode_box(deltas, priors, b, p);
            float lof = (float)c * ofb;
            float4 q = make_float4(db.x + lof, db.y + lof,
                                   db.z + lof, db.w + lof);
            qbox[tid]  = q;
            qarea[tid] = (q.z - q.x) * (q.w - q.y);
        }
        for (int i = tid; i < 8 * HCAP; i += NMS_T) adjB[i] = 0ull;
        __syncthreads();

        // ---- transposed adjacency: wave-task (wi, wj), wi<=wj; lane=col ----
        int hcw = (hc + 63) >> 6;
        int P2  = (hcw * (hcw + 1)) >> 1;
        for (int pair = wave; pair < P2; pair += NMS_T / 64) {
            int wj = 0;
            while ((((wj + 1) * (wj + 2)) >> 1) <= pair) ++wj;  // wave-uniform
            int wi = pair - ((wj * (wj + 1)) >> 1);
            int j  = (wj << 6) + lane;
            float4 qj = qbox[j];
            float  aj = qarea[j];
            int ib = wi << 6;
            uint64_t m = 0ull;
#pragma unroll 8
            for (int i = 0; i < 64; ++i) {
                float4 qi = qbox[ib + i];                 // broadcast read
                float ix1 = fmaxf(qj.x, qi.x), iy1 = fmaxf(qj.y, qi.y);
                float ix2 = fminf(qj.z, qi.z), iy2 = fminf(qj.w, qi.w);
                float inter = fmaxf(ix2 - ix1, 0.0f) * fmaxf(iy2 - iy1, 0.0f);
                float iou = inter / (aj + qarea[ib + i] - inter);
                m |= (uint64_t)(iou > NMS_THR) << i;
            }
            if (wi == wj)                                  // keep i<=lane (diag in)
                m &= (lane == 63) ? ~0ull : ((1ull << (lane + 1)) - 1ull);
            adjB[wi * HCAP + j] = m;
        }
        if (wave == 0 && lane < 8) rk[lane] = 0ull;        // accept masks
        __syncthreads();

        // ---- wave-0 register-only monotonic greedy ----
        if (wave == 0) {
            uint64_t accwA[8];
#pragma unroll
            for (int w = 0; w < 8; ++w) accwA[w] = 0ull;
            int na = 0;
#pragma unroll
            for (int w = 0; w < 8; ++w) {
                if (w < hcw && na < TOPN) {
                    int nInW = hc - (w << 6);
                    uint64_t init = (nInW >= 64) ? ~0ull
                                  : (nInW > 0 ? ((1ull << nInW) - 1ull) : 0ull);
                    uint64_t deadOr = 0ull;
#pragma unroll
                    for (int wp = 0; wp < w; ++wp)
                        deadOr |= adjB[wp * HCAP + (w << 6) + lane] & accwA[wp];
                    uint64_t mycol = adjB[w * HCAP + (w << 6) + lane];
                    uint64_t rem = init & ~__ballot(deadOr != 0ull);
                    uint64_t acc = 0ull;
                    while (rem != 0ull && na < TOPN) {
                        int rr = __ffsll((unsigned long long)rem) - 1;
                        acc |= 1ull << rr;
                        ++na;
                        rem &= ~__ballot(((mycol >> rr) & 1ull) != 0ull);
                    }
                    accwA[w] = acc;
                    if (lane == 0) rk[w] = acc;
                }
            }
            if (lane == 0) naS = na;
        }
        __syncthreads();

        // ---- parallel output write (re-decode; accept order == rank order) --
        if (tid < HCAP) {
            int w = tid >> 6, rr = tid & 63;
            uint64_t aw = rk[w];
            if ((aw >> rr) & 1ull) {
                int idx = (int)__popcll(aw & ((1ull << rr) - 1ull));
                for (int k = 0; k < w; ++k) idx += (int)__popcll(rk[k]);
                uint64_t myk = skey[tid];
                uint32_t oid = 0xFFFFFFFFu - (uint32_t)myk;
                int p = (int)(oid / NLBL);
                int c = (int)(oid - (uint32_t)p * NLBL) + 1;
                float4 db = decode_box(deltas, priors, b, p);
                float* o = out + ((size_t)b * TOPN + idx) * 6;
                o[0] = fminf(fmaxf(db.x, 0.0f), 1.0f);
                o[1] = fminf(fmaxf(db.y, 0.0f), 1.0f);
                o[2] = fminf(fmaxf(db.z, 0.0f), 1.0f);
                o[3] = fminf(fmaxf(db.w, 0.0f), 1.0f);
                o[4] = __uint_as_float((uint32_t)(myk >> 32));
                o[5] = (float)c;
            }
        }
        __syncthreads();
    }

    // ======== EXACT FALLBACK (never with this data) ========
    if (naS < TOPN) {
        // ---- stage 0: rebuild ALL candidates (seg/ovf) from obj ----
        if (tid == 0) ovfC = 0;
        __syncthreads();
        for (int u = wave; u < SEGS; u += NMS_T / 64) {
            int fb = u >> 4, vw = u & 15;          // (block, wave) of v15 mapping
            int pbase = fb * PPB + vw * 4;
            uint64_t* myseg = slots + (size_t)u * SEGW;
            bool pv[4]; float e0[4], e1[4], e2[4], e3[4], inv[4];
            softmax4(obj, b, pbase, lane, pv, e0, e1, e2, e3, inv);
            int cursor = 0;
#pragma unroll
            for (int pp = 0; pp < 4; ++pp) {
                float ev[4] = { e0[pp], e1[pp], e2[pp], e3[pp] };
#pragma unroll
                for (int k = 0; k < 4; ++k) {
                    int c = lane + 64 * k;
                    float prob = ev[k] * inv[pp];
                    bool pass = pv[pp] && (c >= 1) && (c < NCLS) && (prob > SCORE_THR);
                    uint64_t mask = __ballot(pass);
                    if (pass) {
                        uint32_t oid = (uint32_t)((pbase + pp) * NLBL + (c - 1));
                        uint64_t key = ((uint64_t)__float_as_uint(prob) << 32)
                                     | (uint64_t)(0xFFFFFFFFu - oid);
                        int idx = cursor + (int)__popcll(mask & ((1ull << lane) - 1ull));
                        if (idx < SEGW) {
                            myseg[idx] = key;
                        } else {
                            int gi = atomicAdd(&ovfC, 1);
                            if (gi < OVF_CAP) ovfp[gi] = key;
                        }
                    }
                    cursor += (int)__popcll(mask);
                }
            }
            if (lane >= (cursor < SEGW ? cursor : SEGW)) myseg[lane] = 0ull;
        }
        __threadfence_block();
        __syncthreads();
        int n_ovf = ovfC; if (n_ovf > OVF_CAP) n_ovf = OVF_CAP;

        // ---- decode all priors into dboxF (aliases adjB region; fast path
        //      is dead here) + lmax ----
        {
            float lmax = -FLT_MAX;
            for (int p = tid; p < PRIORS; p += NMS_T) {
                float4 d = decode_box(deltas, priors, b, p);
                dboxF[p] = d;
                lmax = fmaxf(lmax, fmaxf(fmaxf(d.x, d.y), fmaxf(d.z, d.w)));
            }
            for (int d = 32; d > 0; d >>= 1)
                lmax = fmaxf(lmax, __shfl_xor(lmax, d, 64));
            if (lane == 0) wredF[wave] = lmax;
        }
        sufx[tid] = 0;
        if (tid == 0) naS = 0;              // restart: rows rewritten identically
        __syncthreads();
        // histogram over ALL candidates (seg + ovf)
        for (int j = tid; j < SLOTS; j += NMS_T) {
            uint64_t k = slots[j];
            if (k) atomicAdd(&sufx[key_stratum(k)], 1);
        }
        for (int j = tid; j < n_ovf; j += NMS_T) {
            uint64_t k = ovfp[j];
            if (k) atomicAdd(&sufx[key_stratum(k)], 1);
        }
        __syncthreads();
        // wave-parallel inclusive suffix sum
        {
            int v = sufx[64 * wave + lane];
            int s = v;
            for (int d = 1; d < 64; d <<= 1) {
                int t = __shfl_down(s, d, 64);
                if (lane + d < 64) s += t;
            }
            if (lane == 0) wtotS[wave] = s;
            __syncthreads();
            if (wave == 0 && lane < NMS_T / 64) {
                int tv = wtotS[lane];
                int ts = tv;
                for (int d = 1; d < NMS_T / 64; d <<= 1) {
                    int t = __shfl_down(ts, d, 64);
                    if (lane + d < NMS_T / 64) ts += t;
                }
                carryS[lane] = ts - tv;
            }
            __syncthreads();
            sufx[64 * wave + lane] = s + carryS[wave];
        }
        // chunk loop (chunks of HCAP=512)
        int curHi = NBINS;
        for (;;) {
            __syncthreads();
            int naCur = naS;
            int A = (curHi < NBINS) ? sufx[curHi] : 0;
            int remaining = sufx[0] - A;
            if (naCur >= TOPN || remaining <= 0 || curHi <= 0) break;
            int target = A + HCAP;
            if (tid == 0) { loS = curHi; cntC = 0; }
            __syncthreads();
            if (tid < curHi) {
                if (sufx[tid] <= target && (tid == 0 || sufx[tid - 1] > target))
                    loS = tid;
            }
            __syncthreads();
            int lo = loS;

            if (lo < curHi) {
                for (int j = tid; j < SLOTS; j += NMS_T) {
                    uint64_t k = slots[j];
                    if (k) {
                        int s = key_stratum(k);
                        if (s >= lo && s < curHi) {
                            int i = atomicAdd(&cntC, 1);
                            if (i < HCAP) skey[i] = k;   // <= HCAP by construction
                        }
                    }
                }
                for (int j = tid; j < n_ovf; j += NMS_T) {
                    uint64_t k = ovfp[j];
                    if (k) {
                        int s = key_stratum(k);
                        if (s >= lo && s < curHi) {
                            int i = atomicAdd(&cntC, 1);
                            if (i < HCAP) skey[i] = k;
                        }
                    }
                }
                __syncthreads();
                if (tid < HCAP && tid >= cntC) skey[tid] = 0ull;
                __syncthreads();
                if (wave == 0) {
                    uint64_t K[8];
                    sort512_desc(skey, K, lane);
                    float ofb;
                    {
                        float v = (lane < NMS_T / 64) ? wredF[lane] : -FLT_MAX;
                        for (int d = 32; d > 0; d >>= 1) v = fmaxf(v, __shfl_xor(v, d, 64));
                        ofb = v + 1.0f;
                    }
                    int na = scan_sorted_w0(K, b, dboxF, ofb, abox, aarea, naS, out, lane);
                    if (lane == 0) naS = na;
                }
                curHi = lo;
            } else {
                // overfull stratum: exact extraction by repeated block argmax
                float ofbT;
                {
                    float v = (lane < NMS_T / 64) ? wredF[lane] : -FLT_MAX;
                    for (int d = 32; d > 0; d >>= 1) v = fmaxf(v, __shfl_xor(v, d, 64));
                    ofbT = v + 1.0f;
                }
                int s = curHi - 1;
                uint64_t lastK = ~0ull;
                for (;;) {
                    __syncthreads();
                    if (naS >= TOPN) break;
                    uint64_t bk = 0ull;
                    for (int j = tid; j < SLOTS; j += NMS_T) {
                        uint64_t k = slots[j];
                        if (k && key_stratum(k) == s && k < lastK && k > bk) bk = k;
                    }
                    for (int j = tid; j < n_ovf; j += NMS_T) {
                        uint64_t k = ovfp[j];
                        if (k && key_stratum(k) == s && k < lastK && k > bk) bk = k;
                    }
                    for (int d = 32; d > 0; d >>= 1) {
                        uint64_t o = __shfl_xor((unsigned long long)bk, d, 64);
                        bk = (o > bk) ? o : bk;
                    }
                    if (lane == 0) rk[wave] = bk;
                    __syncthreads();
                    if (tid == 0) {
                        uint64_t fk = rk[0];
                        for (int w = 1; w < NMS_T / 64; ++w) fk = (rk[w] > fk) ? rk[w] : fk;
                        fkS = fk;
                    }
                    __syncthreads();
                    uint64_t fk = fkS;
                    if (fk == 0ull) break;
                    if (wave == 0) {
                        int nal = naS;
                        nal = scan_step_w0(fk, b, dboxF, ofbT, abox, aarea, nal, out, lane);
                        if (lane == 0) naS = nal;
                    }
                    lastK = fk;
                }
                curHi = s;
            }
        }
    }
    // ---- zero-fill rows naS..99 (harness poisons d_out) ----
    __syncthreads();
    int naF = naS;
    for (int idx = tid; idx < (TOPN - naF) * 6; idx += NMS_T)
        out[(size_t)b * TOPN * 6 + (size_t)naF * 6 + idx] = 0.0f;
}

// ---------------------------------------------------------------------------
extern "C" void kernel_launch(void* const* d_in, const int* in_sizes, int n_in,
                              void* d_out, int out_size, void* d_ws, size_t ws_size,
                              hipStream_t stream)
{
    const float* deltas = (const float*)d_in[0];
    const float* obj    = (const float*)d_in[1];
    const float* priors = (const float*)d_in[2];
    float* out = (float*)d_out;

    char* ws = (char*)d_ws;
    int*      flags = (int*)ws;                             // 64 B
    int*      done  = (int*)(ws + 64);                      // 64 B
    uint64_t* hotA  = (uint64_t*)(ws + 256);                // B*SEGS*HOTW*8 = 770 KB
    uint64_t* segA  = hotA + (size_t)BATCH * SEGS * HOTW;   // B*SLOTS*8 = 6.2 MB (fallback)
    uint64_t* ovfA  = segA + (size_t)BATCH * SLOTS;         // 128 KB (fallback)

    hipMemsetAsync(ws, 0, 128, stream);
    dim3 fg(FBLK2, BATCH, 1);
    fused_kernel<<<fg, NMS_T, 0, stream>>>(deltas, priors, obj, hotA,
                                           flags, done, segA, ovfA, out);
}

// Round 7
// 137.635 us; speedup vs baseline: 2.4413x; 2.4413x over previous
//
#include <hip/hip_runtime.h>
#include <cfloat>
#include <cstdint>

#define BATCH 16
#define PRIORS 3000
#define NCLS 201
#define NLBL 200           // NCLS - 1
#define TOPN 100
#define SCORE_THR 0.02f
#define NMS_THR 0.45f

// v16 (re-run; R6 was an infra container failure, no measurement).
// Two kernels (v15 lesson: per-block __threadfence() election = serialized
// L2 writebacks across 752 blocks, +250 us idle; kernel boundary is the only
// cheap device-wide visibility point).
// Filter changes vs v14:
//  (a) 8 priors/wave (FPPB=32): 32 independent loads in flight, 8 interleaved
//      reduction trees. Per-prior expressions + per-4-prior-segment ballot
//      groupings + slot layout UNCHANGED -> hot set bit-identical.
//  (b) computes per-image gmax = max over all decoded box coords via ONE
//      atomicMax per block (monotone float<->uint key bijection: exact) so
//      nms no longer needs its 3000-prior decode phase for ofb.
// nms v16: collect -> wave-0 sort512 -> ofb from gmax -> qbox re-decode
// (v15-verified bit-exact) -> transposed adjacency -> register-only greedy
// -> parallel output write. Exact fallback (never taken) recomputes all
// candidates from obj, self-contained.
#define FPPB 32                              // priors per block (filter)
#define FBLK ((PRIORS + FPPB - 1) / FPPB)    // 94 blocks/image
#define SEGW 64                              // fallback seg slots per segment
#define SEGS (FBLK * 8)                      // 752 4-prior segments/image
#define SLOTS (SEGS * SEGW)                  // 48128 (fallback ws)
#define HOTW 8                               // hot slots per 4-prior segment
#define OVF_CAP 1024
#define T0 0.08f           // hot threshold: ~315 hot/image (in [105,512] w/ margin)

#define NMS_T 1024
#define NBINS 1024         // strata over (key>>48)-SB_BASE (fallback only)
#define HCAP 512
#define SB_BASE 0x3CA3     // floatbits(0.02) >> 16

__device__ __forceinline__ int key_stratum(uint64_t k) {
    int s = (int)(k >> 48) - SB_BASE;
    return s < 0 ? 0 : (s > NBINS - 1 ? NBINS - 1 : s);
}

// monotone float<->uint order bijection (exact; no NaNs in data)
__device__ __forceinline__ unsigned fkey(float f) {
    unsigned u = __float_as_uint(f);
    return (u & 0x80000000u) ? ~u : (u | 0x80000000u);
}
__device__ __forceinline__ float funkey(unsigned k) {
    return __uint_as_float((k & 0x80000000u) ? (k & 0x7FFFFFFFu) : ~k);
}

// ---------------------------------------------------------------------------
// Decode one prior's box. EXACT expression match with all prior versions.
// Pure function -> identical bits wherever called (verified bit-exact in v15).
// ---------------------------------------------------------------------------
__device__ __forceinline__ float4 decode_box(
    const float* __restrict__ deltas, const float* __restrict__ priors,
    int b, int p)
{
    float4 d4 = ((const float4*)deltas)[(size_t)b * PRIORS + p];
    float4 pr = ((const float4*)priors)[p];
    float cx = d4.x * 0.1f * pr.z + pr.x;
    float cy = d4.y * 0.1f * pr.w + pr.y;
    float w  = expf(d4.z * 0.2f) * pr.z;
    float h  = expf(d4.w * 0.2f) * pr.w;
    return make_float4(cx - 0.5f * w, cy - 0.5f * h,
                       cx + 0.5f * w, cy + 0.5f * h);
}

// ---------------------------------------------------------------------------
// Shared softmax core: NP priors per 64-lane wave, interleaved trees.
// EXACT per-prior expression/order match with all prior bit-exact versions
// (each prior's tree independent -> NP=4 vs 8 changes only ILP, not bits).
// ---------------------------------------------------------------------------
template<int NP>
__device__ __forceinline__ void softmaxN(
    const float* __restrict__ obj, int b, int pbase, int lane,
    bool* pv, float* e0, float* e1, float* e2, float* e3, float* inv)
{
    float v0[NP], v1[NP], v2[NP], v3[NP];
#pragma unroll
    for (int pp = 0; pp < NP; ++pp) {
        int p = pbase + pp;
        pv[pp] = (p < PRIORS);
        const float* x = obj + ((size_t)b * PRIORS + (pv[pp] ? p : PRIORS - 1)) * NCLS;
        v0[pp] = x[lane];
        v1[pp] = x[lane + 64];
        v2[pp] = x[lane + 128];
        v3[pp] = (lane + 192 < NCLS) ? x[lane + 192] : -FLT_MAX;
    }
    float mx[NP];
#pragma unroll
    for (int pp = 0; pp < NP; ++pp)
        mx[pp] = fmaxf(fmaxf(v0[pp], v1[pp]), fmaxf(v2[pp], v3[pp]));
    for (int d = 32; d > 0; d >>= 1) {
#pragma unroll
        for (int pp = 0; pp < NP; ++pp)
            mx[pp] = fmaxf(mx[pp], __shfl_xor(mx[pp], d, 64));
    }
    float se[NP];
#pragma unroll
    for (int pp = 0; pp < NP; ++pp) {
        e0[pp] = expf(v0[pp] - mx[pp]);
        e1[pp] = expf(v1[pp] - mx[pp]);
        e2[pp] = expf(v2[pp] - mx[pp]);
        e3[pp] = (lane + 192 < NCLS) ? expf(v3[pp] - mx[pp]) : 0.0f;
        se[pp] = e0[pp] + e1[pp] + e2[pp] + e3[pp];
    }
    for (int d = 32; d > 0; d >>= 1) {
#pragma unroll
        for (int pp = 0; pp < NP; ++pp)
            se[pp] += __shfl_xor(se[pp], d, 64);
    }
#pragma unroll
    for (int pp = 0; pp < NP; ++pp) inv[pp] = 1.0f / se[pp];
}

// ---------------------------------------------------------------------------
// Kernel B (v16): 8-prior softmax + hot-only per-4-prior-segment emission
// (no atomics in emit) + one atomicMax per block for per-image gmax.
// ---------------------------------------------------------------------------
__global__ __launch_bounds__(256) void score_filter_kernel(
    const float* __restrict__ obj,      // [B][P][NCLS]
    const float* __restrict__ deltas,   // [B][P][4]
    const float* __restrict__ priors,   // [P][4]
    uint64_t*    __restrict__ hotS,     // [B][SEGS][HOTW]  prob > T0 only
    int*         __restrict__ flags,    // [B] hot-overflow flag (memset 0)
    unsigned*    __restrict__ gmax)     // [B] fkey(max decoded coord) (memset 0)
{
    const int b    = blockIdx.y;
    const int wave = threadIdx.x >> 6;
    const int lane = threadIdx.x & 63;
    const int pbase = blockIdx.x * FPPB + wave * 8;
    const int segBase = blockIdx.x * 8 + wave * 2;   // two 4-prior segments/wave

    bool pv[8]; float e0[8], e1[8], e2[8], e3[8], inv[8];
    softmaxN<8>(obj, b, pbase, lane, pv, e0, e1, e2, e3, inv);

#pragma unroll
    for (int half = 0; half < 2; ++half) {
        uint64_t* myhot = hotS + ((size_t)b * SEGS + segBase + half) * HOTW;
        int hcur = 0;
#pragma unroll
        for (int pp4 = 0; pp4 < 4; ++pp4) {
            int pp = half * 4 + pp4;
            float ev[4] = { e0[pp], e1[pp], e2[pp], e3[pp] };
#pragma unroll
            for (int k = 0; k < 4; ++k) {
                int c = lane + 64 * k;
                float prob = ev[k] * inv[pp];
                bool hotp = pv[pp] && (c >= 1) && (c < NCLS) && (prob > T0);
                uint64_t hmask = __ballot(hotp);
                if (hotp) {
                    uint32_t oid = (uint32_t)((pbase + pp) * NLBL + (c - 1));
                    uint64_t key = ((uint64_t)__float_as_uint(prob) << 32)
                                 | (uint64_t)(0xFFFFFFFFu - oid);
                    int hidx = hcur + (int)__popcll(hmask & ((1ull << lane) - 1ull));
                    if (hidx < HOTW) myhot[hidx] = key;
                    else flags[b] = 1;     // exact: force fallback (never taken)
                }
                hcur += (int)__popcll(hmask);
            }
        }
        if (lane < HOTW && lane >= (hcur < HOTW ? hcur : HOTW)) myhot[lane] = 0ull;
    }

    // per-image gmax contribution: wave 0 decodes this block's 32 priors
    // (lanes 32-63 duplicate lanes 0-31: harmless for max). One atomicMax
    // per block (94/image, spread over filter duration, off critical path).
    if (wave == 0) {
        int p = blockIdx.x * FPPB + (lane & 31);
        if (p >= PRIORS) p = PRIORS - 1;             // duplicate: max unchanged
        float4 d = decode_box(deltas, priors, b, p);
        float m = fmaxf(fmaxf(d.x, d.y), fmaxf(d.z, d.w));
        for (int dd = 32; dd > 0; dd >>= 1)
            m = fmaxf(m, __shfl_xor(m, dd, 64));
        if (lane == 0) atomicMax(&gmax[b], fkey(m));
    }
}

// ---------------------------------------------------------------------------
// Wave-0 register bitonic sort of 512 u64 keys (8/lane), descending.
// ---------------------------------------------------------------------------
__device__ __forceinline__ void sort512_desc(const uint64_t* skey,
                                             uint64_t K[8], int lane)
{
#pragma unroll
    for (int r = 0; r < 8; ++r) K[r] = skey[r * 64 + lane];
#pragma unroll
    for (int k2 = 2; k2 <= 512; k2 <<= 1) {
#pragma unroll
        for (int j2 = k2 >> 1; j2 >= 64; j2 >>= 1) {     // register stages
            int j2r = j2 >> 6;
#pragma unroll
            for (int r = 0; r < 8; ++r) {
                if ((r & j2r) == 0) {
                    int rp = r | j2r;
                    bool up = ((((r << 6) + lane) & k2) == 0);
                    uint64_t a = K[r], bb = K[rp];
                    uint64_t mxk = a > bb ? a : bb;
                    uint64_t mnk = a > bb ? bb : a;
                    K[r]  = up ? mxk : mnk;
                    K[rp] = up ? mnk : mxk;
                }
            }
        }
#pragma unroll
        for (int j2 = ((k2 >> 1) < 32 ? (k2 >> 1) : 32); j2 >= 1; j2 >>= 1) {
#pragma unroll
            for (int r = 0; r < 8; ++r) {                // shuffle stages
                uint64_t o = __shfl_xor((unsigned long long)K[r], j2, 64);
                bool up = ((((r << 6) + lane) & k2) == 0);
                bool lower = ((lane & j2) == 0);
                K[r] = (up == lower) ? (K[r] > o ? K[r] : o)
                                     : (K[r] < o ? K[r] : o);
            }
        }
    }
}

// ---------------------------------------------------------------------------
// FALLBACK ONLY: wave-0 batched scan over sorted K[8] (desc).
// ---------------------------------------------------------------------------
__device__ __forceinline__ int scan_sorted_w0(
    const uint64_t K[8], int b, const float4* dbox, float ofb,
    float4* abox, float* aarea, int na, float* __restrict__ out, int lane)
{
#pragma unroll
    for (int r = 0; r < 8; ++r) {
        if (na >= TOPN) break;
        uint64_t myk = K[r];
        bool valid = (myk != 0ull);
        uint32_t oid = 0xFFFFFFFFu - (uint32_t)myk;
        int p = valid ? (int)(oid / NLBL) : 0;
        int c = valid ? ((int)(oid - (uint32_t)p * NLBL) + 1) : 1;
        float4 db = dbox[p];
        float lof = (float)c * ofb;
        float qx1 = db.x + lof, qy1 = db.y + lof;
        float qx2 = db.z + lof, qy2 = db.w + lof;
        float aq = (qx2 - qx1) * (qy2 - qy1);
        bool dead = false;
        for (int l = 0; l < na; ++l) {
            float4 a = abox[l];                    // broadcast LDS read
            float ix1 = fmaxf(qx1, a.x), iy1 = fmaxf(qy1, a.y);
            float ix2 = fminf(qx2, a.z), iy2 = fminf(qy2, a.w);
            float inter = fmaxf(ix2 - ix1, 0.0f) * fmaxf(iy2 - iy1, 0.0f);
            float iou = inter / (aq + aarea[l] - inter);  // NaN>thr==false
            if (iou > NMS_THR) dead = true;
        }
        uint64_t alive = __ballot(valid && !dead);
        while (alive != 0ull && na < TOPN) {
            int j = __ffsll((unsigned long long)alive) - 1;
            float ax1 = __shfl(qx1, j, 64);
            float ay1 = __shfl(qy1, j, 64);
            float ax2 = __shfl(qx2, j, 64);
            float ay2 = __shfl(qy2, j, 64);
            float aa  = __shfl(aq,  j, 64);
            if (lane == j) {                       // accepted lane writes
                abox[na]  = make_float4(qx1, qy1, qx2, qy2);
                aarea[na] = aq;
                float* o = out + ((size_t)b * TOPN + na) * 6;
                o[0] = fminf(fmaxf(db.x, 0.0f), 1.0f);
                o[1] = fminf(fmaxf(db.y, 0.0f), 1.0f);
                o[2] = fminf(fmaxf(db.z, 0.0f), 1.0f);
                o[3] = fminf(fmaxf(db.w, 0.0f), 1.0f);
                o[4] = __uint_as_float((uint32_t)(myk >> 32));
                o[5] = (float)c;
            }
            na++;
            bool mine = ((alive >> lane) & 1ull) != 0ull;
            bool drop = (lane == j);               // force-remove accepted
            if (mine && !drop) {
                float ix1 = fmaxf(qx1, ax1), iy1 = fmaxf(qy1, ay1);
                float ix2 = fminf(qx2, ax2), iy2 = fminf(qy2, ay2);
                float inter = fmaxf(ix2 - ix1, 0.0f) * fmaxf(iy2 - iy1, 0.0f);
                float iou = inter / (aq + aa - inter);
                if (iou > NMS_THR) drop = true;
            }
            alive = __ballot(mine && !drop);
        }
    }
    return na;
}

// ---------------------------------------------------------------------------
// Fallback single-candidate scan step (overfull-stratum path; never taken).
// ---------------------------------------------------------------------------
__device__ __forceinline__ int scan_step_w0(
    uint64_t key, int b, const float4* dbox, float ofb,
    float4* abox, float* aarea, int na, float* __restrict__ out, int lane)
{
    uint32_t oid = 0xFFFFFFFFu - (uint32_t)key;
    int p = (int)(oid / NLBL);
    int c = (int)(oid - (uint32_t)p * NLBL) + 1;
    float4 db = dbox[p];
    float lo = (float)c * ofb;
    float qx1 = db.x + lo, qy1 = db.y + lo;
    float qx2 = db.z + lo, qy2 = db.w + lo;
    float aq = (qx2 - qx1) * (qy2 - qy1);
    bool sup = false;
    for (int l = lane; l < na; l += 64) {
        float4 a = abox[l];
        float ix1 = fmaxf(qx1, a.x), iy1 = fmaxf(qy1, a.y);
        float ix2 = fminf(qx2, a.z), iy2 = fminf(qy2, a.w);
        float inter = fmaxf(ix2 - ix1, 0.0f) * fmaxf(iy2 - iy1, 0.0f);
        float iou = inter / (aq + aarea[l] - inter);
        if (iou > NMS_THR) sup = true;
    }
    if (__ballot(sup) == 0ull) {
        if (lane == 0) {
            abox[na]  = make_float4(qx1, qy1, qx2, qy2);
            aarea[na] = aq;
            float* o = out + ((size_t)b * TOPN + na) * 6;
            o[0] = fminf(fmaxf(db.x, 0.0f), 1.0f);
            o[1] = fminf(fmaxf(db.y, 0.0f), 1.0f);
            o[2] = fminf(fmaxf(db.z, 0.0f), 1.0f);
            o[3] = fminf(fmaxf(db.w, 0.0f), 1.0f);
            o[4] = __uint_as_float((uint32_t)(key >> 32));
            o[5] = (float)c;
        }
        __threadfence_block();
        return na + 1;
    }
    return na;
}

// ---------------------------------------------------------------------------
// Kernel C (v16): one block per image, 1024 threads.
// FAST PATH: collect hot -> wave-0 sort512 -> ofb from gmax -> qbox
// (re-decode) -> transposed adjacency -> register-only monotonic greedy ->
// parallel output write (re-decode). No 3000-prior decode phase.
// EXACT FALLBACK (never with this data): rebuild seg/ovf from obj, decode
// dboxF (aliased over adjB), histogram + chunk + overfull-stratum pipeline.
// ---------------------------------------------------------------------------
__global__ __launch_bounds__(NMS_T) void nms_kernel(
    const float*    __restrict__ deltas,  // [B][P][4]
    const float*    __restrict__ priors,  // [P][4]
    const float*    __restrict__ obj,     // [B][P][NCLS] (fallback recompute)
    const uint64_t* __restrict__ hotS,    // [B][SEGS*HOTW]
    const int*      __restrict__ flags,   // [B] hot-overflow flags
    const unsigned* __restrict__ gmax,    // [B] fkey(max coord)
    uint64_t*       __restrict__ segWS,   // [B][SLOTS]  (fallback scratch)
    uint64_t*       __restrict__ ovfWS,   // [B][OVF_CAP](fallback scratch)
    float*          __restrict__ out)     // [B][TOPN][6]
{
    // ---- LDS: 48 KB aliased region (fast: adjB+qbox+qarea / fb: dbox) ----
    __shared__ __align__(16) char uMem[48 * 1024];
    uint64_t* adjB  = (uint64_t*)uMem;                 // 32 KB (fast)
    float4*   qbox  = (float4*)(uMem + 32 * 1024);     // 8 KB  (fast)
    float*    qarea = (float*)(uMem + 40 * 1024);      // 2 KB  (fast)
    float4*   dboxF = (float4*)uMem;                   // 48 KB (fallback only)
    __shared__ uint64_t skey[HCAP];       // collected/sorted keys (4 KB)
    __shared__ int      sufx[NBINS];      // fallback suffix counts (4 KB)
    __shared__ float4   abox[112];        // accepted boxes (fallback only)
    __shared__ float    aarea[112];
    __shared__ uint64_t rk[NMS_T / 64];   // fast: accept masks / fb: argmax
    __shared__ float    wredF[NMS_T / 64];
    __shared__ int      wtotS[NMS_T / 64];
    __shared__ int      carryS[NMS_T / 64];
    __shared__ int cntC, ovfC, loS, naS;
    __shared__ uint64_t fkS;

    const int b    = blockIdx.x;
    const int tid  = threadIdx.x;
    const int wave = tid >> 6;
    const int lane = tid & 63;
    const uint64_t* hslots = hotS + (size_t)b * SEGS * HOTW;
    uint64_t* slots = segWS + (size_t)b * SLOTS;
    uint64_t* ovfp  = ovfWS + (size_t)b * OVF_CAP;

    if (tid == 0) { cntC = 0; naS = 0; }
    __syncthreads();

    // ---- collect hot keys (ballot-compacted; few tiny LDS atomics) ----
    for (int j = tid; j < SEGS * HOTW; j += NMS_T) {
        uint64_t k = hslots[j];
        uint64_t m = __ballot(k != 0ull);
        if (m) {
            int base = 0;
            if (lane == 0) base = atomicAdd(&cntC, (int)__popcll(m));
            base = __shfl(base, 0, 64);
            if (k) {
                int i = base + (int)__popcll(m & ((1ull << lane) - 1ull));
                if (i < HCAP) skey[i] = k;
            }
        }
    }
    __syncthreads();
    int hc = cntC;                          // uniform
    bool fast = (flags[b] == 0) && (hc <= HCAP);

    if (fast) {
        if (tid < HCAP && tid >= hc) skey[tid] = 0ull;
        __syncthreads();
        if (wave == 0) {
            uint64_t K[8];
            sort512_desc(skey, K, lane);
#pragma unroll
            for (int r = 0; r < 8; ++r) skey[r * 64 + lane] = K[r];
        }
        __syncthreads();                     // sorted skey ready

        float ofb = funkey(gmax[b]) + 1.0f;  // ref's off (exact max bijection)

        // per-rank offset boxes + areas (re-decode; v15-verified bit-exact)
        if (tid < HCAP) {
            uint64_t k = skey[tid];
            bool valid = (k != 0ull);
            uint32_t oid = 0xFFFFFFFFu - (uint32_t)k;
            int p = valid ? (int)(oid / NLBL) : 0;
            int c = valid ? ((int)(oid - (uint32_t)p * NLBL) + 1) : 1;
            float4 db = decode_box(deltas, priors, b, p);
            float lof = (float)c * ofb;
            float4 q = make_float4(db.x + lof, db.y + lof,
                                   db.z + lof, db.w + lof);
            qbox[tid]  = q;
            qarea[tid] = (q.z - q.x) * (q.w - q.y);
        }
        for (int i = tid; i < 8 * HCAP; i += NMS_T) adjB[i] = 0ull;
        __syncthreads();

        // ---- transposed adjacency: wave-task (wi, wj), wi<=wj; lane=col ----
        // bit i of adjB[wi][j] == (rank wi*64+i suppresses rank j), i<=j only
        // for wi==wj (diag kept: accepted rank self-clears via its own bit).
        int hcw = (hc + 63) >> 6;
        int P2  = (hcw * (hcw + 1)) >> 1;
        for (int pair = wave; pair < P2; pair += NMS_T / 64) {
            int wj = 0;
            while ((((wj + 1) * (wj + 2)) >> 1) <= pair) ++wj;  // wave-uniform
            int wi = pair - ((wj * (wj + 1)) >> 1);
            int j  = (wj << 6) + lane;
            float4 qj = qbox[j];
            float  aj = qarea[j];
            int ib = wi << 6;
            uint64_t m = 0ull;
#pragma unroll 8
            for (int i = 0; i < 64; ++i) {
                float4 qi = qbox[ib + i];                 // broadcast read
                float ix1 = fmaxf(qj.x, qi.x), iy1 = fmaxf(qj.y, qi.y);
                float ix2 = fminf(qj.z, qi.z), iy2 = fminf(qj.w, qi.w);
                float inter = fmaxf(ix2 - ix1, 0.0f) * fmaxf(iy2 - iy1, 0.0f);
                float iou = inter / (aj + qarea[ib + i] - inter);
                m |= (uint64_t)(iou > NMS_THR) << i;
            }
            if (wi == wj)                                  // keep i<=lane (diag in)
                m &= (lane == 63) ? ~0ull : ((1ull << (lane + 1)) - 1ull);
            adjB[wi * HCAP + j] = m;
        }
        if (wave == 0 && lane < 8) rk[lane] = 0ull;        // accept masks
        __syncthreads();

        // ---- wave-0 register-only monotonic greedy ----
        if (wave == 0) {
            uint64_t accwA[8];
#pragma unroll
            for (int w = 0; w < 8; ++w) accwA[w] = 0ull;
            int na = 0;
#pragma unroll
            for (int w = 0; w < 8; ++w) {
                if (w < hcw && na < TOPN) {
                    int nInW = hc - (w << 6);
                    uint64_t init = (nInW >= 64) ? ~0ull
                                  : (nInW > 0 ? ((1ull << nInW) - 1ull) : 0ull);
                    uint64_t deadOr = 0ull;
#pragma unroll
                    for (int wp = 0; wp < w; ++wp)
                        deadOr |= adjB[wp * HCAP + (w << 6) + lane] & accwA[wp];
                    uint64_t mycol = adjB[w * HCAP + (w << 6) + lane];
                    uint64_t rem = init & ~__ballot(deadOr != 0ull);
                    uint64_t acc = 0ull;
                    while (rem != 0ull && na < TOPN) {
                        int rr = __ffsll((unsigned long long)rem) - 1;
                        acc |= 1ull << rr;
                        ++na;
                        rem &= ~__ballot(((mycol >> rr) & 1ull) != 0ull);
                    }
                    accwA[w] = acc;
                    if (lane == 0) rk[w] = acc;
                }
            }
            if (lane == 0) naS = na;
        }
        __syncthreads();

        // ---- parallel output write (re-decode; accept order == rank order) --
        if (tid < HCAP) {
            int w = tid >> 6, rr = tid & 63;
            uint64_t aw = rk[w];
            if ((aw >> rr) & 1ull) {
                int idx = (int)__popcll(aw & ((1ull << rr) - 1ull));
                for (int k = 0; k < w; ++k) idx += (int)__popcll(rk[k]);
                uint64_t myk = skey[tid];
                uint32_t oid = 0xFFFFFFFFu - (uint32_t)myk;
                int p = (int)(oid / NLBL);
                int c = (int)(oid - (uint32_t)p * NLBL) + 1;
                float4 db = decode_box(deltas, priors, b, p);
                float* o = out + ((size_t)b * TOPN + idx) * 6;
                o[0] = fminf(fmaxf(db.x, 0.0f), 1.0f);
                o[1] = fminf(fmaxf(db.y, 0.0f), 1.0f);
                o[2] = fminf(fmaxf(db.z, 0.0f), 1.0f);
                o[3] = fminf(fmaxf(db.w, 0.0f), 1.0f);
                o[4] = __uint_as_float((uint32_t)(myk >> 32));
                o[5] = (float)c;
            }
        }
        __syncthreads();
    }

    // ======== EXACT FALLBACK (never with this data) ========
    if (naS < TOPN) {
        // ---- stage 0: rebuild ALL candidates (seg/ovf) from obj ----
        if (tid == 0) ovfC = 0;
        __syncthreads();
        for (int u = wave; u < SEGS; u += NMS_T / 64) {
            int pbase = (u >> 4) * 64 + (u & 15) * 4;   // self-contained 4-prior map
            uint64_t* myseg = slots + (size_t)u * SEGW;
            bool pv[4]; float e0[4], e1[4], e2[4], e3[4], inv[4];
            softmaxN<4>(obj, b, pbase, lane, pv, e0, e1, e2, e3, inv);
            int cursor = 0;
#pragma unroll
            for (int pp = 0; pp < 4; ++pp) {
                float ev[4] = { e0[pp], e1[pp], e2[pp], e3[pp] };
#pragma unroll
                for (int k = 0; k < 4; ++k) {
                    int c = lane + 64 * k;
                    float prob = ev[k] * inv[pp];
                    bool pass = pv[pp] && (c >= 1) && (c < NCLS) && (prob > SCORE_THR);
                    uint64_t mask = __ballot(pass);
                    if (pass) {
                        uint32_t oid = (uint32_t)((pbase + pp) * NLBL + (c - 1));
                        uint64_t key = ((uint64_t)__float_as_uint(prob) << 32)
                                     | (uint64_t)(0xFFFFFFFFu - oid);
                        int idx = cursor + (int)__popcll(mask & ((1ull << lane) - 1ull));
                        if (idx < SEGW) {
                            myseg[idx] = key;
                        } else {
                            int gi = atomicAdd(&ovfC, 1);
                            if (gi < OVF_CAP) ovfp[gi] = key;
                        }
                    }
                    cursor += (int)__popcll(mask);
                }
            }
            if (lane >= (cursor < SEGW ? cursor : SEGW)) myseg[lane] = 0ull;
        }
        __threadfence_block();
        __syncthreads();
        int n_ovf = ovfC; if (n_ovf > OVF_CAP) n_ovf = OVF_CAP;

        // ---- decode all priors into dboxF (aliases adjB; fast path dead) ----
        {
            float lmax = -FLT_MAX;
            for (int p = tid; p < PRIORS; p += NMS_T) {
                float4 d = decode_box(deltas, priors, b, p);
                dboxF[p] = d;
                lmax = fmaxf(lmax, fmaxf(fmaxf(d.x, d.y), fmaxf(d.z, d.w)));
            }
            for (int d = 32; d > 0; d >>= 1)
                lmax = fmaxf(lmax, __shfl_xor(lmax, d, 64));
            if (lane == 0) wredF[wave] = lmax;
        }
        sufx[tid] = 0;
        if (tid == 0) naS = 0;              // restart: rows rewritten identically
        __syncthreads();
        // histogram over ALL candidates (seg + ovf)
        for (int j = tid; j < SLOTS; j += NMS_T) {
            uint64_t k = slots[j];
            if (k) atomicAdd(&sufx[key_stratum(k)], 1);
        }
        for (int j = tid; j < n_ovf; j += NMS_T) {
            uint64_t k = ovfp[j];
            if (k) atomicAdd(&sufx[key_stratum(k)], 1);
        }
        __syncthreads();
        // wave-parallel inclusive suffix sum
        {
            int v = sufx[64 * wave + lane];
            int s = v;
            for (int d = 1; d < 64; d <<= 1) {
                int t = __shfl_down(s, d, 64);
                if (lane + d < 64) s += t;
            }
            if (lane == 0) wtotS[wave] = s;
            __syncthreads();
            if (wave == 0 && lane < NMS_T / 64) {
                int tv = wtotS[lane];
                int ts = tv;
                for (int d = 1; d < NMS_T / 64; d <<= 1) {
                    int t = __shfl_down(ts, d, 64);
                    if (lane + d < NMS_T / 64) ts += t;
                }
                carryS[lane] = ts - tv;
            }
            __syncthreads();
            sufx[64 * wave + lane] = s + carryS[wave];
        }
        // chunk loop (chunks of HCAP=512)
        int curHi = NBINS;
        for (;;) {
            __syncthreads();
            int naCur = naS;
            int A = (curHi < NBINS) ? sufx[curHi] : 0;
            int remaining = sufx[0] - A;
            if (naCur >= TOPN || remaining <= 0 || curHi <= 0) break;
            int target = A + HCAP;
            if (tid == 0) { loS = curHi; cntC = 0; }
            __syncthreads();
            if (tid < curHi) {
                if (sufx[tid] <= target && (tid == 0 || sufx[tid - 1] > target))
                    loS = tid;
            }
            __syncthreads();
            int lo = loS;

            if (lo < curHi) {
                for (int j = tid; j < SLOTS; j += NMS_T) {
                    uint64_t k = slots[j];
                    if (k) {
                        int s = key_stratum(k);
                        if (s >= lo && s < curHi) {
                            int i = atomicAdd(&cntC, 1);
                            if (i < HCAP) skey[i] = k;   // <= HCAP by construction
                        }
                    }
                }
                for (int j = tid; j < n_ovf; j += NMS_T) {
                    uint64_t k = ovfp[j];
                    if (k) {
                        int s = key_stratum(k);
                        if (s >= lo && s < curHi) {
                            int i = atomicAdd(&cntC, 1);
                            if (i < HCAP) skey[i] = k;
                        }
                    }
                }
                __syncthreads();
                if (tid < HCAP && tid >= cntC) skey[tid] = 0ull;
                __syncthreads();
                if (wave == 0) {
                    uint64_t K[8];
                    sort512_desc(skey, K, lane);
                    float ofb;
                    {
                        float v = (lane < NMS_T / 64) ? wredF[lane] : -FLT_MAX;
                        for (int d = 32; d > 0; d >>= 1) v = fmaxf(v, __shfl_xor(v, d, 64));
                        ofb = v + 1.0f;
                    }
                    int na = scan_sorted_w0(K, b, dboxF, ofb, abox, aarea, naS, out, lane);
                    if (lane == 0) naS = na;
                }
                curHi = lo;
            } else {
                // overfull stratum: exact extraction by repeated block argmax
                float ofbT;
                {
                    float v = (lane < NMS_T / 64) ? wredF[lane] : -FLT_MAX;
                    for (int d = 32; d > 0; d >>= 1) v = fmaxf(v, __shfl_xor(v, d, 64));
                    ofbT = v + 1.0f;
                }
                int s = curHi - 1;
                uint64_t lastK = ~0ull;
                for (;;) {
                    __syncthreads();
                    if (naS >= TOPN) break;
                    uint64_t bk = 0ull;
                    for (int j = tid; j < SLOTS; j += NMS_T) {
                        uint64_t k = slots[j];
                        if (k && key_stratum(k) == s && k < lastK && k > bk) bk = k;
                    }
                    for (int j = tid; j < n_ovf; j += NMS_T) {
                        uint64_t k = ovfp[j];
                        if (k && key_stratum(k) == s && k < lastK && k > bk) bk = k;
                    }
                    for (int d = 32; d > 0; d >>= 1) {
                        uint64_t o = __shfl_xor((unsigned long long)bk, d, 64);
                        bk = (o > bk) ? o : bk;
                    }
                    if (lane == 0) rk[wave] = bk;
                    __syncthreads();
                    if (tid == 0) {
                        uint64_t fk = rk[0];
                        for (int w = 1; w < NMS_T / 64; ++w) fk = (rk[w] > fk) ? rk[w] : fk;
                        fkS = fk;
                    }
                    __syncthreads();
                    uint64_t fk = fkS;
                    if (fk == 0ull) break;
                    if (wave == 0) {
                        int nal = naS;
                        nal = scan_step_w0(fk, b, dboxF, ofbT, abox, aarea, nal, out, lane);
                        if (lane == 0) naS = nal;
                    }
                    lastK = fk;
                }
                curHi = s;
            }
        }
    }
    // ---- zero-fill rows naS..99 (harness poisons d_out) ----
    __syncthreads();
    int naF = naS;
    for (int idx = tid; idx < (TOPN - naF) * 6; idx += NMS_T)
        out[(size_t)b * TOPN * 6 + (size_t)naF * 6 + idx] = 0.0f;
}

// ---------------------------------------------------------------------------
extern "C" void kernel_launch(void* const* d_in, const int* in_sizes, int n_in,
                              void* d_out, int out_size, void* d_ws, size_t ws_size,
                              hipStream_t stream)
{
    const float* deltas = (const float*)d_in[0];
    const float* obj    = (const float*)d_in[1];
    const float* priors = (const float*)d_in[2];
    float* out = (float*)d_out;

    char* ws = (char*)d_ws;
    int*      flags = (int*)ws;                             // 64 B
    unsigned* gmaxA = (unsigned*)(ws + 64);                 // 64 B
    uint64_t* hotA  = (uint64_t*)(ws + 256);                // B*SEGS*HOTW*8 = 770 KB
    uint64_t* segA  = hotA + (size_t)BATCH * SEGS * HOTW;   // B*SLOTS*8 = 6.2 MB (fallback)
    uint64_t* ovfA  = segA + (size_t)BATCH * SLOTS;         // 128 KB (fallback)

    hipMemsetAsync(ws, 0, 128, stream);                     // flags + gmax
    dim3 fg(FBLK, BATCH, 1);
    score_filter_kernel<<<fg, 256, 0, stream>>>(obj, deltas, priors,
                                                hotA, flags, gmaxA);
    nms_kernel<<<BATCH, NMS_T, 0, stream>>>(deltas, priors, obj, hotA, flags,
                                            gmaxA, segA, ovfA, out);
}

// Round 8
// 123.253 us; speedup vs baseline: 2.7261x; 1.1167x over previous
//
#include <hip/hip_runtime.h>
#include <cfloat>
#include <cstdint>

#define BATCH 16
#define PRIORS 3000
#define NCLS 201
#define NLBL 200           // NCLS - 1
#define TOPN 100
#define SCORE_THR 0.02f
#define NMS_THR 0.45f

// v17 = v14 (125.5 us champion) + two dispatch-count reductions:
//  (1) NO memset: hot-overflow is signaled IN-BAND by a sentinel key
//      (~0ull, impossible for real keys: high word = prob bits in (0.08,1])
//      written as the wave's LAST store to the segment's slot 7. Filter fully
//      overwrites all hot slots each run and the fallback writes seg/ovf
//      before reading -> no workspace pre-zeroing needed at all.
//  (2) filter blocks 256 -> 1024 threads (FPPB 16 -> 64): identical per-wave
//      4-prior softmax (VGPR ~20, full occupancy preserved), identical
//      global segment indexing -> bit-exact; 4x fewer workgroups.
// v16 lessons: 8-prior ILP raised VGPR and cut TLP on a stall-bound kernel
// (-12 us); per-block device fences are a non-starter (v15). nms keeps
// v14's structure: the 15-wave decode overlaps wave-0's sort for free.
#define FPPB 64                              // priors per block (filter)
#define FBLK ((PRIORS + FPPB - 1) / FPPB)    // 47 blocks/image
#define WPB 16                               // waves per filter block
#define SEGW 64                              // fallback seg slots per segment
#define SEGS (FBLK * WPB)                    // 752 4-prior segments/image
#define SLOTS (SEGS * SEGW)                  // 48128 (fallback ws)
#define HOTW 8                               // hot slots per 4-prior segment
#define OVF_CAP 1024
#define T0 0.08f           // hot threshold: ~315 hot/image (in [105,512] w/ margin)
#define SENTK 0xFFFFFFFFFFFFFFFFull          // overflow sentinel (not a real key)

#define NMS_T 1024
#define NBINS 1024         // strata over (key>>48)-SB_BASE (fallback only)
#define HCAP 512
#define SB_BASE 0x3CA3     // floatbits(0.02) >> 16

__device__ __forceinline__ int key_stratum(uint64_t k) {
    int s = (int)(k >> 48) - SB_BASE;
    return s < 0 ? 0 : (s > NBINS - 1 ? NBINS - 1 : s);
}

// ---------------------------------------------------------------------------
// Shared softmax core: NP priors per 64-lane wave, interleaved trees.
// EXACT per-prior expression/order match with all prior bit-exact versions.
// ---------------------------------------------------------------------------
template<int NP>
__device__ __forceinline__ void softmaxN(
    const float* __restrict__ obj, int b, int pbase, int lane,
    bool* pv, float* e0, float* e1, float* e2, float* e3, float* inv)
{
    float v0[NP], v1[NP], v2[NP], v3[NP];
#pragma unroll
    for (int pp = 0; pp < NP; ++pp) {
        int p = pbase + pp;
        pv[pp] = (p < PRIORS);
        const float* x = obj + ((size_t)b * PRIORS + (pv[pp] ? p : PRIORS - 1)) * NCLS;
        v0[pp] = x[lane];
        v1[pp] = x[lane + 64];
        v2[pp] = x[lane + 128];
        v3[pp] = (lane + 192 < NCLS) ? x[lane + 192] : -FLT_MAX;
    }
    float mx[NP];
#pragma unroll
    for (int pp = 0; pp < NP; ++pp)
        mx[pp] = fmaxf(fmaxf(v0[pp], v1[pp]), fmaxf(v2[pp], v3[pp]));
    for (int d = 32; d > 0; d >>= 1) {
#pragma unroll
        for (int pp = 0; pp < NP; ++pp)
            mx[pp] = fmaxf(mx[pp], __shfl_xor(mx[pp], d, 64));
    }
    float se[NP];
#pragma unroll
    for (int pp = 0; pp < NP; ++pp) {
        e0[pp] = expf(v0[pp] - mx[pp]);
        e1[pp] = expf(v1[pp] - mx[pp]);
        e2[pp] = expf(v2[pp] - mx[pp]);
        e3[pp] = (lane + 192 < NCLS) ? expf(v3[pp] - mx[pp]) : 0.0f;
        se[pp] = e0[pp] + e1[pp] + e2[pp] + e3[pp];
    }
    for (int d = 32; d > 0; d >>= 1) {
#pragma unroll
        for (int pp = 0; pp < NP; ++pp)
            se[pp] += __shfl_xor(se[pp], d, 64);
    }
#pragma unroll
    for (int pp = 0; pp < NP; ++pp) inv[pp] = 1.0f / se[pp];
}

// ---------------------------------------------------------------------------
// Kernel B (v17): 1024-thread blocks, 16 waves x 4 priors. Hot-only
// per-segment emission, zero atomics, zero global counters. Overflow ->
// in-band sentinel as the wave's final store (wins same-address races).
// ---------------------------------------------------------------------------
__global__ __launch_bounds__(1024) void score_filter_kernel(
    const float* __restrict__ obj,      // [B][P][NCLS]
    uint64_t*    __restrict__ hotS)     // [B][SEGS][HOTW]  prob > T0 only
{
    const int b    = blockIdx.y;
    const int wave = threadIdx.x >> 6;
    const int lane = threadIdx.x & 63;
    const int segId = blockIdx.x * WPB + wave;       // global 4-prior-group id
    uint64_t* myhot = hotS + ((size_t)b * SEGS + segId) * HOTW;
    const int pbase = segId * 4;

    bool pv[4]; float e0[4], e1[4], e2[4], e3[4], inv[4];
    softmaxN<4>(obj, b, pbase, lane, pv, e0, e1, e2, e3, inv);

    int hcur = 0;
#pragma unroll
    for (int pp = 0; pp < 4; ++pp) {
        float ev[4] = { e0[pp], e1[pp], e2[pp], e3[pp] };
#pragma unroll
        for (int k = 0; k < 4; ++k) {
            int c = lane + 64 * k;
            float prob = ev[k] * inv[pp];
            bool hotp = pv[pp] && (c >= 1) && (c < NCLS) && (prob > T0);
            uint64_t hmask = __ballot(hotp);
            if (hotp) {
                uint32_t oid = (uint32_t)((pbase + pp) * NLBL + (c - 1));
                uint64_t key = ((uint64_t)__float_as_uint(prob) << 32)
                             | (uint64_t)(0xFFFFFFFFu - oid);
                int hidx = hcur + (int)__popcll(hmask & ((1ull << lane) - 1ull));
                if (hidx < HOTW) myhot[hidx] = key;
            }
            hcur += (int)__popcll(hmask);
        }
    }
    if (lane < HOTW && lane >= (hcur < HOTW ? hcur : HOTW)) myhot[lane] = 0ull;
    // overflow: final store to slot 7 wins program order within the wave
    if (hcur > HOTW && lane == 0) myhot[HOTW - 1] = SENTK;
}

// ---------------------------------------------------------------------------
// Wave-0 register bitonic sort of 512 u64 keys (8/lane), descending.
// ---------------------------------------------------------------------------
__device__ __forceinline__ void sort512_desc(const uint64_t* skey,
                                             uint64_t K[8], int lane)
{
#pragma unroll
    for (int r = 0; r < 8; ++r) K[r] = skey[r * 64 + lane];
#pragma unroll
    for (int k2 = 2; k2 <= 512; k2 <<= 1) {
#pragma unroll
        for (int j2 = k2 >> 1; j2 >= 64; j2 >>= 1) {     // register stages
            int j2r = j2 >> 6;
#pragma unroll
            for (int r = 0; r < 8; ++r) {
                if ((r & j2r) == 0) {
                    int rp = r | j2r;
                    bool up = ((((r << 6) + lane) & k2) == 0);
                    uint64_t a = K[r], bb = K[rp];
                    uint64_t mxk = a > bb ? a : bb;
                    uint64_t mnk = a > bb ? bb : a;
                    K[r]  = up ? mxk : mnk;
                    K[rp] = up ? mnk : mxk;
                }
            }
        }
#pragma unroll
        for (int j2 = ((k2 >> 1) < 32 ? (k2 >> 1) : 32); j2 >= 1; j2 >>= 1) {
#pragma unroll
            for (int r = 0; r < 8; ++r) {                // shuffle stages
                uint64_t o = __shfl_xor((unsigned long long)K[r], j2, 64);
                bool up = ((((r << 6) + lane) & k2) == 0);
                bool lower = ((lane & j2) == 0);
                K[r] = (up == lower) ? (K[r] > o ? K[r] : o)
                                     : (K[r] < o ? K[r] : o);
            }
        }
    }
}

// ---------------------------------------------------------------------------
// FALLBACK ONLY: wave-0 batched scan over sorted K[8] (desc).
// ---------------------------------------------------------------------------
__device__ __forceinline__ int scan_sorted_w0(
    const uint64_t K[8], int b, const float4* __restrict__ dbox, float ofb,
    float4* abox, float* aarea, int na, float* __restrict__ out, int lane)
{
#pragma unroll
    for (int r = 0; r < 8; ++r) {
        if (na >= TOPN) break;
        uint64_t myk = K[r];
        bool valid = (myk != 0ull);
        uint32_t oid = 0xFFFFFFFFu - (uint32_t)myk;
        int p = valid ? (int)(oid / NLBL) : 0;
        int c = valid ? ((int)(oid - (uint32_t)p * NLBL) + 1) : 1;
        float4 db = dbox[p];
        float lof = (float)c * ofb;
        float qx1 = db.x + lof, qy1 = db.y + lof;
        float qx2 = db.z + lof, qy2 = db.w + lof;
        float aq = (qx2 - qx1) * (qy2 - qy1);
        bool dead = false;
        for (int l = 0; l < na; ++l) {
            float4 a = abox[l];                    // broadcast LDS read
            float ix1 = fmaxf(qx1, a.x), iy1 = fmaxf(qy1, a.y);
            float ix2 = fminf(qx2, a.z), iy2 = fminf(qy2, a.w);
            float inter = fmaxf(ix2 - ix1, 0.0f) * fmaxf(iy2 - iy1, 0.0f);
            float iou = inter / (aq + aarea[l] - inter);  // NaN>thr==false
            if (iou > NMS_THR) dead = true;
        }
        uint64_t alive = __ballot(valid && !dead);
        while (alive != 0ull && na < TOPN) {
            int j = __ffsll((unsigned long long)alive) - 1;
            float ax1 = __shfl(qx1, j, 64);
            float ay1 = __shfl(qy1, j, 64);
            float ax2 = __shfl(qx2, j, 64);
            float ay2 = __shfl(qy2, j, 64);
            float aa  = __shfl(aq,  j, 64);
            if (lane == j) {                       // accepted lane writes
                abox[na]  = make_float4(qx1, qy1, qx2, qy2);
                aarea[na] = aq;
                float* o = out + ((size_t)b * TOPN + na) * 6;
                o[0] = fminf(fmaxf(db.x, 0.0f), 1.0f);
                o[1] = fminf(fmaxf(db.y, 0.0f), 1.0f);
                o[2] = fminf(fmaxf(db.z, 0.0f), 1.0f);
                o[3] = fminf(fmaxf(db.w, 0.0f), 1.0f);
                o[4] = __uint_as_float((uint32_t)(myk >> 32));
                o[5] = (float)c;
            }
            na++;
            bool mine = ((alive >> lane) & 1ull) != 0ull;
            bool drop = (lane == j);               // force-remove accepted
            if (mine && !drop) {
                float ix1 = fmaxf(qx1, ax1), iy1 = fmaxf(qy1, ay1);
                float ix2 = fminf(qx2, ax2), iy2 = fminf(qy2, ay2);
                float inter = fmaxf(ix2 - ix1, 0.0f) * fmaxf(iy2 - iy1, 0.0f);
                float iou = inter / (aq + aa - inter);
                if (iou > NMS_THR) drop = true;
            }
            alive = __ballot(mine && !drop);
        }
    }
    return na;
}

// ---------------------------------------------------------------------------
// Fallback single-candidate scan step (overfull-stratum path; never taken).
// ---------------------------------------------------------------------------
__device__ __forceinline__ int scan_step_w0(
    uint64_t key, int b, const float4* __restrict__ dbox, float ofb,
    float4* abox, float* aarea, int na, float* __restrict__ out, int lane)
{
    uint32_t oid = 0xFFFFFFFFu - (uint32_t)key;
    int p = (int)(oid / NLBL);
    int c = (int)(oid - (uint32_t)p * NLBL) + 1;
    float4 db = dbox[p];
    float lo = (float)c * ofb;
    float qx1 = db.x + lo, qy1 = db.y + lo;
    float qx2 = db.z + lo, qy2 = db.w + lo;
    float aq = (qx2 - qx1) * (qy2 - qy1);
    bool sup = false;
    for (int l = lane; l < na; l += 64) {
        float4 a = abox[l];
        float ix1 = fmaxf(qx1, a.x), iy1 = fmaxf(qy1, a.y);
        float ix2 = fminf(qx2, a.z), iy2 = fminf(qy2, a.w);
        float inter = fmaxf(ix2 - ix1, 0.0f) * fmaxf(iy2 - iy1, 0.0f);
        float iou = inter / (aq + aarea[l] - inter);
        if (iou > NMS_THR) sup = true;
    }
    if (__ballot(sup) == 0ull) {
        if (lane == 0) {
            abox[na]  = make_float4(qx1, qy1, qx2, qy2);
            aarea[na] = aq;
            float* o = out + ((size_t)b * TOPN + na) * 6;
            o[0] = fminf(fmaxf(db.x, 0.0f), 1.0f);
            o[1] = fminf(fmaxf(db.y, 0.0f), 1.0f);
            o[2] = fminf(fmaxf(db.z, 0.0f), 1.0f);
            o[3] = fminf(fmaxf(db.w, 0.0f), 1.0f);
            o[4] = __uint_as_float((uint32_t)(key >> 32));
            o[5] = (float)c;
        }
        __threadfence_block();
        return na + 1;
    }
    return na;
}

// ---------------------------------------------------------------------------
// Kernel C (v17 = v14): one block per image, 1024 threads.
// FAST PATH: sentinel-aware collect -> wave-0 sort512 || waves 1-15 decode
// (dbox LDS + wredF) -> offset-box table -> transposed adjacency ->
// register-only monotonic greedy -> parallel output write.
// EXACT FALLBACK (sentinel, hc>512, or accepts<100; never with this data):
// rebuild seg/ovf from obj, then histogram + chunk + overfull-stratum.
// ---------------------------------------------------------------------------
__global__ __launch_bounds__(NMS_T) void nms_kernel(
    const float*    __restrict__ deltas,  // [B][P][4]
    const float*    __restrict__ priors,  // [P][4]
    const float*    __restrict__ obj,     // [B][P][NCLS] (fallback recompute)
    const uint64_t* __restrict__ hotS,    // [B][SEGS*HOTW]
    uint64_t*       __restrict__ segWS,   // [B][SLOTS]  (fallback scratch)
    uint64_t*       __restrict__ ovfWS,   // [B][OVF_CAP](fallback scratch)
    float*          __restrict__ out)     // [B][TOPN][6]
{
    __shared__ float4   dbox[PRIORS];     // 48 KB decoded boxes
    __shared__ int      sufx[NBINS];      // fallback suffix counts (4 KB)
    __shared__ uint64_t skey[HCAP];       // collected/sorted keys (4 KB)
    __shared__ float4   qbox[HCAP];       // per-rank offset boxes (8 KB)
    __shared__ float    qarea[HCAP];      // per-rank areas (2 KB)
    __shared__ uint64_t adjB[8 * HCAP];   // transposed adjacency (32 KB)
    __shared__ float4   abox[112];        // accepted boxes (fallback only)
    __shared__ float    aarea[112];
    __shared__ uint64_t rk[NMS_T / 64];   // fast: accept masks / fb: argmax
    __shared__ float    wredF[NMS_T / 64];
    __shared__ int      wtotS[NMS_T / 64];
    __shared__ int      carryS[NMS_T / 64];
    __shared__ int cntC, ovfC, loS, naS, sflagS;
    __shared__ uint64_t fkS;

    const int b    = blockIdx.x;
    const int tid  = threadIdx.x;
    const int wave = tid >> 6;
    const int lane = tid & 63;
    const uint64_t* hslots = hotS + (size_t)b * SEGS * HOTW;
    uint64_t* slots = segWS + (size_t)b * SLOTS;
    uint64_t* ovfp  = ovfWS + (size_t)b * OVF_CAP;

    if (tid == 0) { cntC = 0; naS = 0; sflagS = 0; }
    if (lane == 0) wredF[wave] = -FLT_MAX;
    __syncthreads();

    // ---- collect hot keys (sentinel-aware, ballot-compacted) ----
    for (int j = tid; j < SEGS * HOTW; j += NMS_T) {
        uint64_t k = hslots[j];
        if (k == SENTK) { sflagS = 1; k = 0ull; }   // overflow -> fallback
        uint64_t m = __ballot(k != 0ull);
        if (m) {
            int base = 0;
            if (lane == 0) base = atomicAdd(&cntC, (int)__popcll(m));
            base = __shfl(base, 0, 64);
            if (k) {
                int i = base + (int)__popcll(m & ((1ull << lane) - 1ull));
                if (i < HCAP) skey[i] = k;
            }
        }
    }
    __syncthreads();
    int hc = cntC;                          // uniform
    bool fast = (sflagS == 0) && (hc <= HCAP);
    bool decoded = false;

    if (fast) {
        if (tid < HCAP && tid >= hc) skey[tid] = 0ull;
        __syncthreads();
        if (wave == 0) {
            // sort 512 keys in registers, write back sorted order
            uint64_t K[8];
            sort512_desc(skey, K, lane);
#pragma unroll
            for (int r = 0; r < 8; ++r) skey[r * 64 + lane] = K[r];
        } else {
            // waves 1-15: decode 3000 priors -> LDS dbox (200 each) + max
            int base0 = (wave - 1) * 200;
            float lmax = -FLT_MAX;
            for (int p = base0 + lane; p < base0 + 200; p += 64) {
                float4 d4 = ((const float4*)deltas)[(size_t)b * PRIORS + p];
                float4 pr = ((const float4*)priors)[p];
                float cx = d4.x * 0.1f * pr.z + pr.x;
                float cy = d4.y * 0.1f * pr.w + pr.y;
                float w  = expf(d4.z * 0.2f) * pr.z;
                float h  = expf(d4.w * 0.2f) * pr.w;
                float x1 = cx - 0.5f * w, y1 = cy - 0.5f * h;
                float x2 = cx + 0.5f * w, y2 = cy + 0.5f * h;
                dbox[p] = make_float4(x1, y1, x2, y2);
                lmax = fmaxf(lmax, fmaxf(fmaxf(x1, y1), fmaxf(x2, y2)));
            }
            for (int d = 32; d > 0; d >>= 1)
                lmax = fmaxf(lmax, __shfl_xor(lmax, d, 64));
            if (lane == 0) wredF[wave] = lmax;
        }
        decoded = true;
        __syncthreads();                     // sorted skey + dbox + wredF ready

        // block-uniform ofb = max(all decoded coords) + 1 (ref's off)
        float v = wredF[lane & 15];
        for (int d = 8; d > 0; d >>= 1) v = fmaxf(v, __shfl_xor(v, d, 64));
        float ofb = v + 1.0f;

        // per-rank offset boxes + areas (identical exprs to scan paths)
        if (tid < HCAP) {
            uint64_t k = skey[tid];
            bool valid = (k != 0ull);
            uint32_t oid = 0xFFFFFFFFu - (uint32_t)k;
            int p = valid ? (int)(oid / NLBL) : 0;
            int c = valid ? ((int)(oid - (uint32_t)p * NLBL) + 1) : 1;
            float4 db = dbox[p];
            float lof = (float)c * ofb;
            float4 q = make_float4(db.x + lof, db.y + lof,
                                   db.z + lof, db.w + lof);
            qbox[tid]  = q;
            qarea[tid] = (q.z - q.x) * (q.w - q.y);
        }
        for (int i = tid; i < 8 * HCAP; i += NMS_T) adjB[i] = 0ull;
        __syncthreads();

        // ---- transposed adjacency: wave-task (wi, wj), wi<=wj; lane=col ----
        // bit i of adjB[wi][j] == (rank wi*64+i suppresses rank j), i<=j only
        // for wi==wj (diag kept: accepted rank self-clears via its own bit).
        int hcw = (hc + 63) >> 6;
        int P2  = (hcw * (hcw + 1)) >> 1;
        for (int pair = wave; pair < P2; pair += NMS_T / 64) {
            int wj = 0;
            while ((((wj + 1) * (wj + 2)) >> 1) <= pair) ++wj;  // wave-uniform
            int wi = pair - ((wj * (wj + 1)) >> 1);
            int j  = (wj << 6) + lane;
            float4 qj = qbox[j];
            float  aj = qarea[j];
            int ib = wi << 6;
            uint64_t m = 0ull;
#pragma unroll 8
            for (int i = 0; i < 64; ++i) {
                float4 qi = qbox[ib + i];                 // broadcast read
                float ix1 = fmaxf(qj.x, qi.x), iy1 = fmaxf(qj.y, qi.y);
                float ix2 = fminf(qj.z, qi.z), iy2 = fminf(qj.w, qi.w);
                float inter = fmaxf(ix2 - ix1, 0.0f) * fmaxf(iy2 - iy1, 0.0f);
                float iou = inter / (aj + qarea[ib + i] - inter);
                m |= (uint64_t)(iou > NMS_THR) << i;
            }
            if (wi == wj)                                  // keep i<=lane (diag in)
                m &= (lane == 63) ? ~0ull : ((1ull << (lane + 1)) - 1ull);
            adjB[wi * HCAP + j] = m;
        }
        if (wave == 0 && lane < 8) rk[lane] = 0ull;        // accept masks
        __syncthreads();

        // ---- wave-0 register-only monotonic greedy ----
        if (wave == 0) {
            uint64_t accwA[8];
#pragma unroll
            for (int w = 0; w < 8; ++w) accwA[w] = 0ull;
            int na = 0;
#pragma unroll
            for (int w = 0; w < 8; ++w) {
                if (w < hcw && na < TOPN) {
                    int nInW = hc - (w << 6);
                    uint64_t init = (nInW >= 64) ? ~0ull
                                  : (nInW > 0 ? ((1ull << nInW) - 1ull) : 0ull);
                    uint64_t deadOr = 0ull;
#pragma unroll
                    for (int wp = 0; wp < w; ++wp)
                        deadOr |= adjB[wp * HCAP + (w << 6) + lane] & accwA[wp];
                    uint64_t mycol = adjB[w * HCAP + (w << 6) + lane];
                    uint64_t rem = init & ~__ballot(deadOr != 0ull);
                    uint64_t acc = 0ull;
                    while (rem != 0ull && na < TOPN) {
                        int rr = __ffsll((unsigned long long)rem) - 1;
                        acc |= 1ull << rr;
                        ++na;
                        rem &= ~__ballot(((mycol >> rr) & 1ull) != 0ull);
                    }
                    accwA[w] = acc;
                    if (lane == 0) rk[w] = acc;
                }
            }
            if (lane == 0) naS = na;
        }
        __syncthreads();

        // ---- parallel output write: accept order == rank order ----
        if (tid < HCAP) {
            int w = tid >> 6, rr = tid & 63;
            uint64_t aw = rk[w];
            if ((aw >> rr) & 1ull) {
                int idx = (int)__popcll(aw & ((1ull << rr) - 1ull));
                for (int k = 0; k < w; ++k) idx += (int)__popcll(rk[k]);
                uint64_t myk = skey[tid];
                uint32_t oid = 0xFFFFFFFFu - (uint32_t)myk;
                int p = (int)(oid / NLBL);
                int c = (int)(oid - (uint32_t)p * NLBL) + 1;
                float4 db = dbox[p];
                float* o = out + ((size_t)b * TOPN + idx) * 6;
                o[0] = fminf(fmaxf(db.x, 0.0f), 1.0f);
                o[1] = fminf(fmaxf(db.y, 0.0f), 1.0f);
                o[2] = fminf(fmaxf(db.z, 0.0f), 1.0f);
                o[3] = fminf(fmaxf(db.w, 0.0f), 1.0f);
                o[4] = __uint_as_float((uint32_t)(myk >> 32));
                o[5] = (float)c;
            }
        }
        __syncthreads();
    }

    // ======== EXACT FALLBACK (never with this data) ========
    if (naS < TOPN) {
        // ---- stage 0: rebuild ALL candidates (seg/ovf) from obj ----
        if (tid == 0) ovfC = 0;
        __syncthreads();
        for (int u = wave; u < SEGS; u += NMS_T / 64) {
            int pbase = u * 4;                  // self-contained 4-prior map
            uint64_t* myseg = slots + (size_t)u * SEGW;
            bool pv[4]; float e0[4], e1[4], e2[4], e3[4], inv[4];
            softmaxN<4>(obj, b, pbase, lane, pv, e0, e1, e2, e3, inv);
            int cursor = 0;
#pragma unroll
            for (int pp = 0; pp < 4; ++pp) {
                float ev[4] = { e0[pp], e1[pp], e2[pp], e3[pp] };
#pragma unroll
                for (int k = 0; k < 4; ++k) {
                    int c = lane + 64 * k;
                    float prob = ev[k] * inv[pp];
                    bool pass = pv[pp] && (c >= 1) && (c < NCLS) && (prob > SCORE_THR);
                    uint64_t mask = __ballot(pass);
                    if (pass) {
                        uint32_t oid = (uint32_t)((pbase + pp) * NLBL + (c - 1));
                        uint64_t key = ((uint64_t)__float_as_uint(prob) << 32)
                                     | (uint64_t)(0xFFFFFFFFu - oid);
                        int idx = cursor + (int)__popcll(mask & ((1ull << lane) - 1ull));
                        if (idx < SEGW) {
                            myseg[idx] = key;
                        } else {
                            int gi = atomicAdd(&ovfC, 1);
                            if (gi < OVF_CAP) ovfp[gi] = key;
                        }
                    }
                    cursor += (int)__popcll(mask);
                }
            }
            if (lane >= (cursor < SEGW ? cursor : SEGW)) myseg[lane] = 0ull;
        }
        __threadfence_block();
        __syncthreads();
        int n_ovf = ovfC; if (n_ovf > OVF_CAP) n_ovf = OVF_CAP;

        if (!decoded) {
            float lmax = -FLT_MAX;
            for (int p = tid; p < PRIORS; p += NMS_T) {
                float4 d4 = ((const float4*)deltas)[(size_t)b * PRIORS + p];
                float4 pr = ((const float4*)priors)[p];
                float cx = d4.x * 0.1f * pr.z + pr.x;
                float cy = d4.y * 0.1f * pr.w + pr.y;
                float w  = expf(d4.z * 0.2f) * pr.z;
                float h  = expf(d4.w * 0.2f) * pr.w;
                float x1 = cx - 0.5f * w, y1 = cy - 0.5f * h;
                float x2 = cx + 0.5f * w, y2 = cy + 0.5f * h;
                dbox[p] = make_float4(x1, y1, x2, y2);
                lmax = fmaxf(lmax, fmaxf(fmaxf(x1, y1), fmaxf(x2, y2)));
            }
            for (int d = 32; d > 0; d >>= 1)
                lmax = fmaxf(lmax, __shfl_xor(lmax, d, 64));
            if (lane == 0) wredF[wave] = lmax;
        }
        sufx[tid] = 0;
        if (tid == 0) naS = 0;              // restart: rows rewritten identically
        __syncthreads();
        // histogram over ALL candidates (seg + ovf)
        for (int j = tid; j < SLOTS; j += NMS_T) {
            uint64_t k = slots[j];
            if (k) atomicAdd(&sufx[key_stratum(k)], 1);
        }
        for (int j = tid; j < n_ovf; j += NMS_T) {
            uint64_t k = ovfp[j];
            if (k) atomicAdd(&sufx[key_stratum(k)], 1);
        }
        __syncthreads();
        // wave-parallel inclusive suffix sum
        {
            int v = sufx[64 * wave + lane];
            int s = v;
            for (int d = 1; d < 64; d <<= 1) {
                int t = __shfl_down(s, d, 64);
                if (lane + d < 64) s += t;
            }
            if (lane == 0) wtotS[wave] = s;
            __syncthreads();
            if (wave == 0 && lane < NMS_T / 64) {
                int tv = wtotS[lane];
                int ts = tv;
                for (int d = 1; d < NMS_T / 64; d <<= 1) {
                    int t = __shfl_down(ts, d, 64);
                    if (lane + d < NMS_T / 64) ts += t;
                }
                carryS[lane] = ts - tv;
            }
            __syncthreads();
            sufx[64 * wave + lane] = s + carryS[wave];
        }
        // chunk loop (chunks of HCAP=512)
        int curHi = NBINS;
        for (;;) {
            __syncthreads();
            int naCur = naS;
            int A = (curHi < NBINS) ? sufx[curHi] : 0;
            int remaining = sufx[0] - A;
            if (naCur >= TOPN || remaining <= 0 || curHi <= 0) break;
            int target = A + HCAP;
            if (tid == 0) { loS = curHi; cntC = 0; }
            __syncthreads();
            if (tid < curHi) {
                if (sufx[tid] <= target && (tid == 0 || sufx[tid - 1] > target))
                    loS = tid;
            }
            __syncthreads();
            int lo = loS;

            if (lo < curHi) {
                for (int j = tid; j < SLOTS; j += NMS_T) {
                    uint64_t k = slots[j];
                    if (k) {
                        int s = key_stratum(k);
                        if (s >= lo && s < curHi) {
                            int i = atomicAdd(&cntC, 1);
                            if (i < HCAP) skey[i] = k;   // <= HCAP by construction
                        }
                    }
                }
                for (int j = tid; j < n_ovf; j += NMS_T) {
                    uint64_t k = ovfp[j];
                    if (k) {
                        int s = key_stratum(k);
                        if (s >= lo && s < curHi) {
                            int i = atomicAdd(&cntC, 1);
                            if (i < HCAP) skey[i] = k;
                        }
                    }
                }
                __syncthreads();
                if (tid < HCAP && tid >= cntC) skey[tid] = 0ull;
                __syncthreads();
                if (wave == 0) {
                    uint64_t K[8];
                    sort512_desc(skey, K, lane);
                    float ofb;
                    {
                        float v = (lane < NMS_T / 64) ? wredF[lane] : -FLT_MAX;
                        for (int d = 32; d > 0; d >>= 1) v = fmaxf(v, __shfl_xor(v, d, 64));
                        ofb = v + 1.0f;
                    }
                    int na = scan_sorted_w0(K, b, dbox, ofb, abox, aarea, naS, out, lane);
                    if (lane == 0) naS = na;
                }
                curHi = lo;
            } else {
                // overfull stratum: exact extraction by repeated block argmax
                float ofbT;
                {
                    float v = (lane < NMS_T / 64) ? wredF[lane] : -FLT_MAX;
                    for (int d = 32; d > 0; d >>= 1) v = fmaxf(v, __shfl_xor(v, d, 64));
                    ofbT = v + 1.0f;
                }
                int s = curHi - 1;
                uint64_t lastK = ~0ull;
                for (;;) {
                    __syncthreads();
                    if (naS >= TOPN) break;
                    uint64_t bk = 0ull;
                    for (int j = tid; j < SLOTS; j += NMS_T) {
                        uint64_t k = slots[j];
                        if (k && key_stratum(k) == s && k < lastK && k > bk) bk = k;
                    }
                    for (int j = tid; j < n_ovf; j += NMS_T) {
                        uint64_t k = ovfp[j];
                        if (k && key_stratum(k) == s && k < lastK && k > bk) bk = k;
                    }
                    for (int d = 32; d > 0; d >>= 1) {
                        uint64_t o = __shfl_xor((unsigned long long)bk, d, 64);
                        bk = (o > bk) ? o : bk;
                    }
                    if (lane == 0) rk[wave] = bk;
                    __syncthreads();
                    if (tid == 0) {
                        uint64_t fk = rk[0];
                        for (int w = 1; w < NMS_T / 64; ++w) fk = (rk[w] > fk) ? rk[w] : fk;
                        fkS = fk;
                    }
                    __syncthreads();
                    uint64_t fk = fkS;
                    if (fk == 0ull) break;
                    if (wave == 0) {
                        int nal = naS;
                        nal = scan_step_w0(fk, b, dbox, ofbT, abox, aarea, nal, out, lane);
                        if (lane == 0) naS = nal;
                    }
                    lastK = fk;
                }
                curHi = s;
            }
        }
    }
    // ---- zero-fill rows naS..99 (harness poisons d_out) ----
    __syncthreads();
    int naF = naS;
    for (int idx = tid; idx < (TOPN - naF) * 6; idx += NMS_T)
        out[(size_t)b * TOPN * 6 + (size_t)naF * 6 + idx] = 0.0f;
}

// ---------------------------------------------------------------------------
extern "C" void kernel_launch(void* const* d_in, const int* in_sizes, int n_in,
                              void* d_out, int out_size, void* d_ws, size_t ws_size,
                              hipStream_t stream)
{
    const float* deltas = (const float*)d_in[0];
    const float* obj    = (const float*)d_in[1];
    const float* priors = (const float*)d_in[2];
    float* out = (float*)d_out;

    // no memset needed: filter fully overwrites hot slots (sentinel in-band);
    // fallback scratch (seg/ovf) is write-before-read.
    uint64_t* hotA = (uint64_t*)d_ws;                       // B*SEGS*HOTW*8 = 770 KB
    uint64_t* segA = hotA + (size_t)BATCH * SEGS * HOTW;    // B*SLOTS*8 = 6.2 MB (fallback)
    uint64_t* ovfA = segA + (size_t)BATCH * SLOTS;          // 128 KB (fallback)

    dim3 fg(FBLK, BATCH, 1);
    score_filter_kernel<<<fg, NMS_T, 0, stream>>>(obj, hotA);
    nms_kernel<<<BATCH, NMS_T, 0, stream>>>(deltas, priors, obj, hotA,
                                            segA, ovfA, out);
}